// Round 10
// baseline (296.676 us; speedup 1.0000x reference)
//
#include <hip/hip_runtime.h>
#include <hip/hip_bf16.h>

typedef __bf16 bf16;
typedef __attribute__((ext_vector_type(8))) __bf16 bf16x8;
typedef __attribute__((ext_vector_type(4))) __bf16 bf16x4;
typedef __attribute__((ext_vector_type(4))) float f32x4;
typedef __attribute__((ext_vector_type(16))) float f32x16;

#define LSP 4096   // H*W
#define CCH 256

__device__ __forceinline__ void gl2lds16(const bf16* g, bf16* l) {
  __builtin_amdgcn_global_load_lds(
      (const __attribute__((address_space(1))) unsigned int*)g,
      (__attribute__((address_space(3))) unsigned int*)l, 16, 0, 0);
}

__device__ __forceinline__ f32x4 mfma16(bf16x8 a, bf16x8 b, f32x4 c) {
  return __builtin_amdgcn_mfma_f32_16x16x32_bf16(a, b, c, 0, 0, 0);
}
__device__ __forceinline__ f32x16 mfma32(bf16x8 a, bf16x8 b, f32x16 c) {
  return __builtin_amdgcn_mfma_f32_32x32x16_bf16(a, b, c, 0, 0, 0);
}

// ---------------------------------------------------------------------------
// Weight f32 -> bf16. Wq,Wk direct; Wv TRANSPOSED (WvT[cin][och]); Wo direct;
// W1 INTERLEAVED and PRE-SCALED by g_ffn (row 2a = W1g[a], 2a+1 = W1g[a+512]);
// W2 direct.
// ---------------------------------------------------------------------------
__global__ __launch_bounds__(256) void cvt_w_kernel(
    const float* __restrict__ wq, const float* __restrict__ wk,
    const float* __restrict__ wv, const float* __restrict__ wo,
    const float* __restrict__ w1, const float* __restrict__ w2,
    const float* __restrict__ gff, bf16* __restrict__ out) {
  int e = blockIdx.x * 256 + threadIdx.x;   // grid 2560 -> 655360 exact
  if (e < 65536)        { out[e] = (bf16)wq[e]; }
  else if (e < 131072)  { out[e] = (bf16)wk[e - 65536]; }
  else if (e < 196608)  {
    int e2 = e - 131072;            // e2 = och*256 + cin
    int och = e2 >> 8, cin = e2 & 255;
    out[131072 + cin * 256 + och] = (bf16)wv[e2];   // WvT
  }
  else if (e < 262144)  { out[e] = (bf16)wo[e - 196608]; }
  else if (e < 524288)  {
    int e2 = e - 262144;            // m*256 + k, m in [0,1024)
    int m = e2 >> 8, k = e2 & 255;
    int mp = (m < 512) ? (2 * m) : (2 * (m - 512) + 1);
    out[262144 + mp * 256 + k] = (bf16)(w1[e2] * gff[k]);  // W1g interleaved
  }
  else                  { out[e] = (bf16)w2[e - 524288]; }
}

// ---------------------------------------------------------------------------
// Per-m FFN1 constants: cvec[0..511]=W1[m]@b_ffn+b1[m], [512..1023]=W1[m]@g_ffn,
// [1024..1535] / [1536..2047] = same for m+512. grid 4 x 256.
// ---------------------------------------------------------------------------
__global__ __launch_bounds__(256) void w1vec_kernel(
    const float* __restrict__ w1, const float* __restrict__ b1,
    const float* __restrict__ gff, const float* __restrict__ bff,
    float* __restrict__ cvec) {
  int m = blockIdx.x * 256 + threadIdx.x;   // 0..1023
  const float* row = w1 + (size_t)m * 256;
  float sb = 0.f, sg = 0.f;
  #pragma unroll 8
  for (int c = 0; c < 256; c += 4) {
    f32x4 w = *(const f32x4*)&row[c];
    f32x4 g = *(const f32x4*)&gff[c];
    f32x4 bb = *(const f32x4*)&bff[c];
    #pragma unroll
    for (int j = 0; j < 4; ++j) { sb += w[j] * bb[j]; sg += w[j] * g[j]; }
  }
  if (m < 512) {
    cvec[m] = sb + b1[m];
    cvec[512 + m] = sg;
  } else {
    cvec[512 + m] = sb + b1[m];       // 1024 + (m-512)
    cvec[1024 + m] = sg;              // 1536 + (m-512)
  }
}

// ---------------------------------------------------------------------------
// Tiled LayerNorm over channels. Input f32 [b][c][l]. Tile = 256c x 64l.
// DUAL: also write normed [l][c].  RAW: also write RAW x as bf16 [l][c]
// (for residual reads downstream).
// ---------------------------------------------------------------------------
template <int DUAL, int RAW>
__global__ __launch_bounds__(256) void ln_tile_kernel(
    const float* __restrict__ x, const float* __restrict__ gam,
    const float* __restrict__ bet, bf16* __restrict__ out_cl,
    bf16* __restrict__ out_lc, bf16* __restrict__ out_raw) {
  const int l0 = blockIdx.x * 64;
  const int b  = blockIdx.y;
  const int tid = threadIdx.x;
  __shared__ bf16 Tt[256 * 64];          // 32 KB, swizzled
  __shared__ float red[2][16][64];       // 8 KB
  __shared__ float mu_s[64], rs_s[64];

  const float* px = x + (size_t)b * CCH * LSP + l0;
  const int colq = (tid & 15) * 4;
  f32x4 s = {0.f, 0.f, 0.f, 0.f}, q = {0.f, 0.f, 0.f, 0.f};
  #pragma unroll
  for (int it = 0; it < 16; ++it) {
    int c = it * 16 + (tid >> 4);
    f32x4 v = *(const f32x4*)&px[(size_t)c * LSP + colq];
    s += v;
    q += v * v;
    bf16x4 h;
    #pragma unroll
    for (int j = 0; j < 4; ++j) h[j] = (bf16)v[j];
    int colp = colq ^ (((c >> 3) & 7) << 3);
    *(bf16x4*)&Tt[c * 64 + colp] = h;
  }
  #pragma unroll
  for (int j = 0; j < 4; ++j) {
    red[0][tid >> 4][colq + j] = s[j];
    red[1][tid >> 4][colq + j] = q[j];
  }
  __syncthreads();
  if (tid < 64) {
    float S = 0.f, Q = 0.f;
    #pragma unroll
    for (int k = 0; k < 16; ++k) { S += red[0][k][tid]; Q += red[1][k][tid]; }
    float m = S * (1.f / 256.f);
    mu_s[tid] = m;
    rs_s[tid] = rsqrtf(Q * (1.f / 256.f) - m * m + 1e-5f);
  }
  __syncthreads();

  #pragma unroll
  for (int it = 0; it < 8; ++it) {
    int ch = it * 256 + tid;
    int c = ch >> 3, col8 = (ch & 7) * 8;
    int colp = col8 ^ (((c >> 3) & 7) << 3);
    bf16x8 h = *(const bf16x8*)&Tt[c * 64 + colp];
    f32x4 m0 = *(const f32x4*)&mu_s[col8];
    f32x4 m1 = *(const f32x4*)&mu_s[col8 + 4];
    f32x4 r0 = *(const f32x4*)&rs_s[col8];
    f32x4 r1 = *(const f32x4*)&rs_s[col8 + 4];
    float g = gam[c], be = bet[c];
    bf16x8 o;
    #pragma unroll
    for (int j = 0; j < 4; ++j) {
      o[j]     = (bf16)(((float)h[j] - m0[j]) * r0[j] * g + be);
      o[4 + j] = (bf16)(((float)h[4 + j] - m1[j]) * r1[j] * g + be);
    }
    *(bf16x8*)&out_cl[((size_t)b * CCH + c) * LSP + l0 + col8] = o;
  }

  if constexpr (DUAL) {
    #pragma unroll
    for (int it = 0; it < 8; ++it) {
      int ch = it * 256 + tid;
      int l = ch >> 5, cch = ch & 31;
      int c0 = cch * 8;
      int lp = l ^ ((cch & 7) << 3);
      float mu = mu_s[l], rs = rs_s[l];
      f32x4 g0 = *(const f32x4*)&gam[c0];
      f32x4 g1 = *(const f32x4*)&gam[c0 + 4];
      f32x4 b0 = *(const f32x4*)&bet[c0];
      f32x4 b1 = *(const f32x4*)&bet[c0 + 4];
      bf16x8 o;
      #pragma unroll
      for (int j = 0; j < 4; ++j) {
        float h0 = (float)Tt[(c0 + j) * 64 + lp];
        float h1 = (float)Tt[(c0 + 4 + j) * 64 + lp];
        o[j]     = (bf16)((h0 - mu) * rs * g0[j] + b0[j]);
        o[4 + j] = (bf16)((h1 - mu) * rs * g1[j] + b1[j]);
      }
      *(bf16x8*)&out_lc[((size_t)b * LSP + l0 + l) * CCH + c0] = o;
    }
  }
  if constexpr (RAW) {
    #pragma unroll
    for (int it = 0; it < 8; ++it) {
      int ch = it * 256 + tid;
      int l = ch >> 5, cch = ch & 31;
      int c0 = cch * 8;
      int lp = l ^ ((cch & 7) << 3);
      bf16x8 o;
      #pragma unroll
      for (int j = 0; j < 4; ++j) {
        o[j]     = Tt[(c0 + j) * 64 + lp];
        o[4 + j] = Tt[(c0 + 4 + j) * 64 + lp];
      }
      *(bf16x8*)&out_raw[((size_t)b * LSP + l0 + l) * CCH + c0] = o;
    }
  }
}

// ---------------------------------------------------------------------------
// Gram: G2part[chunk][b][j][i] = sum_{l in chunk} sar_cl[b][j][l]*opt_cl[b][i][l]
// ---------------------------------------------------------------------------
__global__ __launch_bounds__(256) void gram_kernel(
    const bf16* __restrict__ sar_cl, const bf16* __restrict__ opt_cl,
    float* __restrict__ part) {
  const int tile = blockIdx.x, chunk = blockIdx.y, b = blockIdx.z;
  const int tid = threadIdx.x, lane = tid & 63, w = tid >> 6;
  const int j0 = (tile >> 1) * 128 + (w >> 1) * 64;
  const int i0 = (tile & 1) * 128 + (w & 1) * 64;
  const int l0 = chunk * 1024;
  const bf16* sj = sar_cl + ((size_t)b * CCH + j0 + (lane & 31)) * LSP + l0;
  const bf16* oi = opt_cl + ((size_t)b * CCH + i0 + (lane & 31)) * LSP + l0;
  f32x16 acc[2][2];
  #pragma unroll
  for (int mt = 0; mt < 2; ++mt)
    #pragma unroll
    for (int nt = 0; nt < 2; ++nt)
      #pragma unroll
      for (int r = 0; r < 16; ++r) acc[mt][nt][r] = 0.f;
  #pragma unroll 4
  for (int ks = 0; ks < 64; ++ks) {
    int lofs = ks * 16 + (lane >> 5) * 8;
    bf16x8 a0 = *(const bf16x8*)&sj[lofs];
    bf16x8 a1 = *(const bf16x8*)&sj[32 * LSP + lofs];
    bf16x8 b0 = *(const bf16x8*)&oi[lofs];
    bf16x8 b1 = *(const bf16x8*)&oi[32 * LSP + lofs];
    acc[0][0] = mfma32(a0, b0, acc[0][0]);
    acc[0][1] = mfma32(a0, b1, acc[0][1]);
    acc[1][0] = mfma32(a1, b0, acc[1][0]);
    acc[1][1] = mfma32(a1, b1, acc[1][1]);
  }
  float* op = part + ((size_t)chunk * 16 + b) * 65536;
  #pragma unroll
  for (int mt = 0; mt < 2; ++mt)
    #pragma unroll
    for (int nt = 0; nt < 2; ++nt)
      #pragma unroll
      for (int r = 0; r < 16; ++r) {
        int row = j0 + mt * 32 + (r & 3) + 8 * (r >> 2) + 4 * (lane >> 5);
        int col = i0 + nt * 32 + (lane & 31);
        op[(size_t)row * 256 + col] = acc[mt][nt][r];
      }
}

// ---------------------------------------------------------------------------
// Reduce Gram partials (4 chunks) -> G2 bf16 [b][j][i]
// ---------------------------------------------------------------------------
__global__ __launch_bounds__(256) void greduce_kernel(
    const float* __restrict__ part, bf16* __restrict__ G2) {
  size_t e = ((size_t)blockIdx.x * 256 + threadIdx.x) * 8;  // grid 512
  float a[8];
  #pragma unroll
  for (int i = 0; i < 8; ++i) a[i] = 0.f;
  #pragma unroll
  for (int ch = 0; ch < 4; ++ch) {
    f32x4 p0 = *(const f32x4*)&part[ch * 1048576ull + e];
    f32x4 p1 = *(const f32x4*)&part[ch * 1048576ull + e + 4];
    #pragma unroll
    for (int i = 0; i < 4; ++i) { a[i] += p0[i]; a[4 + i] += p1[i]; }
  }
  bf16x8 o;
  #pragma unroll
  for (int i = 0; i < 8; ++i) o[i] = (bf16)a[i];
  *(bf16x8*)&G2[e] = o;
}

// ---------------------------------------------------------------------------
// Fold: per (b,h): M1[c][j] = sum_i Wq_h[c][i]*G2[j][i],
// S[c][d] = sum_j M1[c][j]*Wk_h[d][j], softmax rows -> P,
// UT[b][cin][h*32+c] = sum_d WvT[cin][h*32+d]*P[c][d].
// ---------------------------------------------------------------------------
__global__ __launch_bounds__(256) void fold2_kernel(
    const bf16* __restrict__ G2, const bf16* __restrict__ Wq,
    const bf16* __restrict__ Wk, const bf16* __restrict__ WvT,
    bf16* __restrict__ UT) {
  const int bh = blockIdx.x;
  const int b = bh >> 3, h = bh & 7;
  const int tid = threadIdx.x, lane = tid & 63, w = tid >> 6;
  __shared__ bf16 M1[32 * 256];
  __shared__ float Sp[4][1024];
  __shared__ float S[1024];
  __shared__ bf16 P[1024];

  const bf16* gq = Wq + (size_t)(h * 32) * 256;
  const bf16* g2b = G2 + (size_t)b * 65536;
  #pragma unroll
  for (int mt = 0; mt < 2; ++mt)
    #pragma unroll
    for (int nt = 0; nt < 4; ++nt) {
      f32x4 acc = {0.f, 0.f, 0.f, 0.f};
      #pragma unroll
      for (int ks = 0; ks < 8; ++ks) {
        bf16x8 a = *(const bf16x8*)&gq[(size_t)(mt * 16 + (lane & 15)) * 256 +
                                       ks * 32 + (lane >> 4) * 8];
        bf16x8 bb = *(const bf16x8*)&g2b[
            (size_t)(w * 64 + nt * 16 + (lane & 15)) * 256 + ks * 32 +
            (lane >> 4) * 8];
        acc = mfma16(a, bb, acc);
      }
      #pragma unroll
      for (int r = 0; r < 4; ++r)
        M1[(mt * 16 + (lane >> 4) * 4 + r) * 256 + w * 64 + nt * 16 +
           (lane & 15)] = (bf16)acc[r];
    }
  __syncthreads();

  const bf16* gk = Wk + (size_t)(h * 32) * 256;
  #pragma unroll
  for (int mt = 0; mt < 2; ++mt)
    #pragma unroll
    for (int dt = 0; dt < 2; ++dt) {
      f32x4 acc = {0.f, 0.f, 0.f, 0.f};
      #pragma unroll
      for (int kk = 0; kk < 2; ++kk) {
        bf16x8 a = *(const bf16x8*)&M1[(mt * 16 + (lane & 15)) * 256 + w * 64 +
                                       kk * 32 + (lane >> 4) * 8];
        bf16x8 bb = *(const bf16x8*)&gk[(size_t)(dt * 16 + (lane & 15)) * 256 +
                                        w * 64 + kk * 32 + (lane >> 4) * 8];
        acc = mfma16(a, bb, acc);
      }
      #pragma unroll
      for (int r = 0; r < 4; ++r)
        Sp[w][(mt * 16 + (lane >> 4) * 4 + r) * 32 + dt * 16 + (lane & 15)] =
            acc[r];
    }
  __syncthreads();
  #pragma unroll
  for (int i = 0; i < 4; ++i) {
    int e = tid + 256 * i;
    S[e] = (Sp[0][e] + Sp[1][e] + Sp[2][e] + Sp[3][e]) * 0.17677669529663687f;
  }
  __syncthreads();
  if (tid < 32) {
    float m = -1e30f;
    #pragma unroll
    for (int d = 0; d < 32; ++d) m = fmaxf(m, S[tid * 32 + d]);
    float sum = 0.f;
    float ex[32];
    #pragma unroll
    for (int d = 0; d < 32; ++d) {
      ex[d] = __expf(S[tid * 32 + d] - m);
      sum += ex[d];
    }
    float inv = 1.f / sum;
    #pragma unroll
    for (int d = 0; d < 32; ++d) P[tid * 32 + d] = (bf16)(ex[d] * inv);
  }
  __syncthreads();

  bf16x8 bfrag[2];
  #pragma unroll
  for (int ct = 0; ct < 2; ++ct)
    bfrag[ct] =
        *(const bf16x8*)&P[(ct * 16 + (lane & 15)) * 32 + (lane >> 4) * 8];
  bf16* outb = UT + (size_t)b * 65536 + h * 32;
  #pragma unroll
  for (int t = 0; t < 4; ++t) {
    int cin16 = w * 64 + t * 16;
    bf16x8 afrag = *(const bf16x8*)&WvT[(size_t)(cin16 + (lane & 15)) * 256 +
                                        h * 32 + (lane >> 4) * 8];
    #pragma unroll
    for (int ct = 0; ct < 2; ++ct) {
      f32x4 acc = {0.f, 0.f, 0.f, 0.f};
      acc = mfma16(afrag, bfrag[ct], acc);
      int c = ct * 16 + (lane & 15);
      int cinr = cin16 + (lane >> 4) * 4;
      #pragma unroll
      for (int r = 0; r < 4; ++r)
        outb[(size_t)(cinr + r) * 256 + c] = (bf16)acc[r];
    }
  }
}

// ---------------------------------------------------------------------------
// Small GEMM for Wfold: out bf16 [b][256][256] = Wo @ UT   (128x128 tiles)
// ---------------------------------------------------------------------------
__global__ __launch_bounds__(256) void wfold_kernel(
    const bf16* __restrict__ Aw, const bf16* __restrict__ Bx,
    bf16* __restrict__ outp) {
  const int tid = threadIdx.x;
  const int lane = tid & 63;
  const int wave = tid >> 6;
  const int wr = wave >> 1, wc = wave & 1;
  const int l0 = blockIdx.x * 128;
  const int m0 = blockIdx.y * 128;
  const int b  = blockIdx.z;
  constexpr int NB = 4096;
  __shared__ bf16 smem[4 * NB];
  bf16* As = smem;
  bf16* Bs = smem + 2 * NB;
  const bf16* Ag = Aw + (size_t)m0 * 256;
  const bf16* Bg = Bx + ((size_t)b * 256 + l0) * 256;
  auto stage = [&](int buf, int k0) {
    #pragma unroll
    for (int i = 0; i < 2; ++i) {
      int ch = i * 256 + tid;
      int r  = ch >> 2;
      int c8 = (ch & 3) * 8;
      gl2lds16(Ag + (size_t)r * 256 + k0 + c8, As + buf * NB + ch * 8);
      gl2lds16(Bg + (size_t)r * 256 + k0 + c8, Bs + buf * NB + ch * 8);
    }
  };
  f32x4 acc[4][4];
  #pragma unroll
  for (int mi = 0; mi < 4; ++mi)
    #pragma unroll
    for (int ni = 0; ni < 4; ++ni)
      #pragma unroll
      for (int r = 0; r < 4; ++r) acc[mi][ni][r] = 0.f;
  stage(0, 0);
  for (int kt = 0; kt < 8; ++kt) {
    __syncthreads();
    if (kt + 1 < 8) stage((kt + 1) & 1, (kt + 1) * 32);
    const bf16* Ab = As + (kt & 1) * NB;
    const bf16* Bb = Bs + (kt & 1) * NB;
    bf16x8 af[4], bfr[4];
    #pragma unroll
    for (int mi = 0; mi < 4; ++mi)
      af[mi] = *(const bf16x8*)&Ab[(wr * 64 + mi * 16 + (lane & 15)) * 32 +
                                   (lane >> 4) * 8];
    #pragma unroll
    for (int ni = 0; ni < 4; ++ni)
      bfr[ni] = *(const bf16x8*)&Bb[(wc * 64 + ni * 16 + (lane & 15)) * 32 +
                                    (lane >> 4) * 8];
    #pragma unroll
    for (int mi = 0; mi < 4; ++mi)
      #pragma unroll
      for (int ni = 0; ni < 4; ++ni)
        acc[mi][ni] = mfma16(af[mi], bfr[ni], acc[mi][ni]);
  }
  const int mq = m0 + wr * 64 + (lane >> 4) * 4;
  const int lq = l0 + wc * 64 + (lane & 15);
  #pragma unroll
  for (int mi = 0; mi < 4; ++mi)
    #pragma unroll
    for (int ni = 0; ni < 4; ++ni) {
      int l = lq + ni * 16, mb = mq + mi * 16;
      #pragma unroll
      for (int r = 0; r < 4; ++r)
        outp[((size_t)b * 256 + mb + r) * 256 + l] = (bf16)acc[mi][ni][r];
    }
}

// ---------------------------------------------------------------------------
// Fused x-GEMM + residual + LN-stats (M=256, N=64, K=256).
// Residual now read from RAW bf16 optical [b][l][c] (coalesced) instead of
// f32 [b][c][l] strided (saves 100 MB HBM).
// ---------------------------------------------------------------------------
__global__ __launch_bounds__(256) void xgemm_stats_kernel(
    const bf16* __restrict__ Wfold, const bf16* __restrict__ sar_lc,
    const bf16* __restrict__ opt_raw, bf16* __restrict__ xout,
    float* __restrict__ stats) {
  const int tid = threadIdx.x, lane = tid & 63, w = tid >> 6;
  const int l0 = blockIdx.x * 64;
  const int b  = blockIdx.y;
  __shared__ __align__(16) char smem[43520];
  bf16* X = (bf16*)smem;
  float* red = (float*)(smem + 40960);

  const bf16* Ag = Wfold + (size_t)b * 65536;
  const bf16* Bg = sar_lc + ((size_t)b * LSP + l0) * CCH;

  auto stage = [&](int buf, int k0) {
    bf16* As = (bf16*)(smem + buf * 16384);
    bf16* Bs = (bf16*)(smem + 32768 + buf * 4096);
    #pragma unroll
    for (int i = 0; i < 4; ++i) {
      int ch = i * 256 + tid;
      int r = ch >> 2, c8 = (ch & 3) * 8;
      gl2lds16(Ag + (size_t)r * 256 + k0 + c8, &As[ch * 8]);
    }
    {
      int r = tid >> 2, c8 = (tid & 3) * 8;
      gl2lds16(Bg + (size_t)r * 256 + k0 + c8, &Bs[tid * 8]);
    }
  };

  f32x4 acc[4][4];
  #pragma unroll
  for (int mi = 0; mi < 4; ++mi)
    #pragma unroll
    for (int ni = 0; ni < 4; ++ni)
      #pragma unroll
      for (int r = 0; r < 4; ++r) acc[mi][ni][r] = 0.f;

  stage(0, 0);
  for (int kt = 0; kt < 8; ++kt) {
    __syncthreads();
    if (kt < 7) stage((kt + 1) & 1, (kt + 1) * 32);
    const bf16* Ab = (const bf16*)(smem + (kt & 1) * 16384);
    const bf16* Bb = (const bf16*)(smem + 32768 + (kt & 1) * 4096);
    bf16x8 af[4], bfr[4];
    #pragma unroll
    for (int mi = 0; mi < 4; ++mi)
      af[mi] = *(const bf16x8*)&Ab[(w * 64 + mi * 16 + (lane & 15)) * 32 +
                                   (lane >> 4) * 8];
    #pragma unroll
    for (int ni = 0; ni < 4; ++ni)
      bfr[ni] = *(const bf16x8*)&Bb[(ni * 16 + (lane & 15)) * 32 +
                                    (lane >> 4) * 8];
    #pragma unroll
    for (int mi = 0; mi < 4; ++mi)
      #pragma unroll
      for (int ni = 0; ni < 4; ++ni)
        acc[mi][ni] = mfma16(af[mi], bfr[ni], acc[mi][ni]);
  }
  __syncthreads();   // all LDS frag reads done; As/Bs region reused as X

  const int cb = w * 64 + (lane >> 4) * 4;
  const int lb = lane & 15;
  float s[4], q[4];
  #pragma unroll
  for (int ni = 0; ni < 4; ++ni) { s[ni] = 0.f; q[ni] = 0.f; }
  #pragma unroll
  for (int mi = 0; mi < 4; ++mi)
    #pragma unroll
    for (int ni = 0; ni < 4; ++ni) {
      int c = cb + mi * 16, ll = lb + ni * 16;
      bf16x4 o4 = *(const bf16x4*)&opt_raw[((size_t)b * LSP + l0 + ll) * CCH + c];
      bf16x4 hx;
      #pragma unroll
      for (int r = 0; r < 4; ++r) {
        float v = acc[mi][ni][r] + (float)o4[r];
        s[ni] += v; q[ni] += v * v;
        hx[r] = (bf16)v;
      }
      *(bf16x4*)&X[ll * 260 + c] = hx;
    }
  #pragma unroll
  for (int ni = 0; ni < 4; ++ni) {
    s[ni] += __shfl_xor(s[ni], 16);
    s[ni] += __shfl_xor(s[ni], 32);
    q[ni] += __shfl_xor(q[ni], 16);
    q[ni] += __shfl_xor(q[ni], 32);
  }
  if ((lane >> 4) == 0) {
    #pragma unroll
    for (int ni = 0; ni < 4; ++ni) {
      red[(0 * 4 + w) * 64 + ni * 16 + lb] = s[ni];
      red[(4 + w) * 64 + ni * 16 + lb] = q[ni];
    }
  }
  __syncthreads();
  if (tid < 64) {
    float S4 = red[0 * 64 + tid] + red[1 * 64 + tid] + red[2 * 64 + tid] +
               red[3 * 64 + tid];
    float Q4 = red[4 * 64 + tid] + red[5 * 64 + tid] + red[6 * 64 + tid] +
               red[7 * 64 + tid];
    float m = S4 * (1.f / 256.f);
    float rs = rsqrtf(Q4 * (1.f / 256.f) - m * m + 1e-5f);
    float* st = stats + ((size_t)b * LSP + l0 + tid) * 2;
    st[0] = m;
    st[1] = rs;
  }
  __syncthreads();
  #pragma unroll
  for (int it = 0; it < 8; ++it) {
    int cid = it * 256 + tid;            // 2048 chunks of 16B
    int l = cid >> 5, c0 = (cid & 31) * 8;
    bf16x8 v = *(const bf16x8*)&X[l * 260 + c0];
    *(bf16x8*)&xout[((size_t)b * LSP + l0 + l) * CCH + c0] = v;
  }
}

// ---------------------------------------------------------------------------
// FUSED FFN: per l-tile of 64, computes d_out = x + W2 @ gate(LNaffine(W1g@x)).
// No g intermediate in HBM. 512 threads, 8 waves. Per hidden-chunk (8 total,
// 64 gate-ch each): GEMM1 (W1i-chunk frags DIRECT from global L2, 8m-split ->
// no duplicate reads; x-frags from LDS) -> gate+folded-LN -> g_chunk in LDS
// (double-buffered, ONE barrier per chunk); GEMM2 accumulates W2-chunk
// (direct global) x g_chunk. Epilogue: 2-round LDS transpose + b2 + bf16 x
// residual -> f32 d_out [b][c][l].
// LDS: xs [64 l][256 k] swizzled (chunk c' = c ^ (l&31)) 32 KB + g2 2x[64][72]
// 18 KB = 50 KB -> 2 blocks/CU at 4 waves/SIMD.
// ---------------------------------------------------------------------------
__global__ __launch_bounds__(512, 4) void ffn_fused_kernel(
    const bf16* __restrict__ W1i, const bf16* __restrict__ W2,
    const bf16* __restrict__ xb, float* __restrict__ out,
    const float* __restrict__ cvec, const float* __restrict__ b2v,
    const float* __restrict__ stats) {
  __shared__ __align__(16) char smem[51200];
  bf16* xs = (bf16*)smem;                       // [64][256] swizzled
  const int tid = threadIdx.x;
  const int lane = tid & 63;
  const int w = tid >> 6;
  const int l0 = blockIdx.x * 64;
  const int b  = blockIdx.y;
  const int qq = lane >> 4;
  const int lr = lane & 15;

  // stage x tile: 2048 chunks of 16B, source col pre-swizzled
  const bf16* xg = xb + ((size_t)b * LSP + l0) * CCH;
  #pragma unroll
  for (int i = 0; i < 4; ++i) {
    int qi = i * 512 + tid;
    int r = qi >> 5, c = qi & 31;
    int gc = c ^ (r & 31);
    gl2lds16(xg + (size_t)r * CCH + gc * 8, xs + qi * 8);
  }

  // per-l LN stats (hoisted; same for all chunks)
  const float* stb = stats + ((size_t)b * LSP + l0) * 2;
  float muv[4], rsv[4];
  #pragma unroll
  for (int nq = 0; nq < 4; ++nq) {
    int l = nq * 16 + lr;
    muv[nq] = stb[l * 2];
    rsv[nq] = stb[l * 2 + 1];
  }

  f32x4 acc2[2][4];
  #pragma unroll
  for (int mt = 0; mt < 2; ++mt)
    #pragma unroll
    for (int nq = 0; nq < 4; ++nq)
      #pragma unroll
      for (int r = 0; r < 4; ++r) acc2[mt][nq][r] = 0.f;

  __syncthreads();   // xs ready (implicit vmcnt drain by syncthreads)

  for (int chunk = 0; chunk < 8; ++chunk) {
    bf16* g2 = (bf16*)(smem + 32768 + (chunk & 1) * 9216);  // [64][72]

    // ---- GEMM1: rows chunk*128 + w*16 .. +16, all 64 l, K=256 ----
    f32x4 acc1[4];
    #pragma unroll
    for (int nq = 0; nq < 4; ++nq)
      #pragma unroll
      for (int r = 0; r < 4; ++r) acc1[nq][r] = 0.f;
    const bf16* w1p = W1i + (size_t)(chunk * 128 + w * 16 + lr) * CCH;
    #pragma unroll
    for (int ks = 0; ks < 8; ++ks) {
      bf16x8 a = *(const bf16x8*)&w1p[ks * 32 + qq * 8];
      #pragma unroll
      for (int nq = 0; nq < 4; ++nq) {
        int l = nq * 16 + lr;
        int cc = (ks * 4 + qq) ^ (l & 31);
        bf16x8 bb = *(const bf16x8*)&xs[l * 256 + cc * 8];
        acc1[nq] = mfma16(a, bb, acc1[nq]);
      }
    }
    // gate + folded LN -> g2[l][gc], gc = w*8 + qq*2 (+0/+1)
    {
      int ag = chunk * 64 + w * 8 + qq * 2;
      float be1a = cvec[ag],        ga1a = cvec[512 + ag];
      float be2a = cvec[1024 + ag], ga2a = cvec[1536 + ag];
      float be1b = cvec[ag + 1],        ga1b = cvec[512 + ag + 1];
      float be2b = cvec[1024 + ag + 1], ga2b = cvec[1536 + ag + 1];
      int gc0 = w * 8 + qq * 2;
      #pragma unroll
      for (int nq = 0; nq < 4; ++nq) {
        int l = nq * 16 + lr;
        float mrs = muv[nq] * rsv[nq];
        float h1a = rsv[nq] * acc1[nq][0] + be1a - mrs * ga1a;
        float h2a = rsv[nq] * acc1[nq][1] + be2a - mrs * ga2a;
        float h1b = rsv[nq] * acc1[nq][2] + be1b - mrs * ga1b;
        float h2b = rsv[nq] * acc1[nq][3] + be2b - mrs * ga2b;
        bf16 gv0 = (bf16)(h1a * h2a), gv1 = (bf16)(h1b * h2b);
        unsigned u = ((unsigned)*(unsigned short*)&gv1 << 16) |
                     (unsigned)*(unsigned short*)&gv0;
        *(unsigned*)&g2[l * 72 + gc0] = u;
      }
    }
    __syncthreads();   // g2 visible; prev-buf GEMM2 readers done 2 barriers ago

    // ---- GEMM2: rows w*32 .. +32 of 256, K = 64 gc in 2 steps ----
    const bf16* w2p = W2 + (size_t)(w * 32 + lr) * 512 + chunk * 64;
    #pragma unroll
    for (int ks2 = 0; ks2 < 2; ++ks2) {
      bf16x8 a0 = *(const bf16x8*)&w2p[ks2 * 32 + qq * 8];
      bf16x8 a1 = *(const bf16x8*)&w2p[16 * 512 + ks2 * 32 + qq * 8];
      #pragma unroll
      for (int nq = 0; nq < 4; ++nq) {
        int l = nq * 16 + lr;
        bf16x8 bb = *(const bf16x8*)&g2[l * 72 + ks2 * 32 + qq * 8];
        acc2[0][nq] = mfma16(a0, bb, acc2[0][nq]);
        acc2[1][nq] = mfma16(a1, bb, acc2[1][nq]);
      }
    }
  }
  __syncthreads();   // all GEMM2 reads done; smem reused as transpose buf

  // ---- epilogue: + b2 + x residual, transpose, f32 [b][c][l] ----
  float* lds_f = (float*)smem;   // [128 c][68 l] f32 = 34.8 KB
  #pragma unroll
  for (int h = 0; h < 2; ++h) {
    if ((w >> 2) == h) {
      #pragma unroll
      for (int mt = 0; mt < 2; ++mt) {
        int cbase = w * 32 + mt * 16 + qq * 4;          // global c
        int crl = cbase - h * 128;                      // c within round
        f32x4 b4 = *(const f32x4*)&b2v[cbase];
        #pragma unroll
        for (int nq = 0; nq < 4; ++nq) {
          int l = nq * 16 + lr;
          bf16x4 xr4 = *(const bf16x4*)&xb[((size_t)b * LSP + l0 + l) * CCH +
                                           cbase];
          #pragma unroll
          for (int r = 0; r < 4; ++r)
            lds_f[(crl + r) * 68 + l] = acc2[mt][nq][r] + b4[r] + (float)xr4[r];
        }
      }
    }
    __syncthreads();
    #pragma unroll
    for (int it = 0; it < 4; ++it) {
      int cid = it * 512 + tid;          // 2048 chunks of 16B
      int c = cid >> 4, lch = cid & 15;
      f32x4 v = *(const f32x4*)&lds_f[c * 68 + lch * 4];
      *(f32x4*)&out[((size_t)b * CCH + h * 128 + c) * LSP + l0 + lch * 4] = v;
    }
    __syncthreads();
  }
}

// ---------------------------------------------------------------------------
extern "C" void kernel_launch(void* const* d_in, const int* in_sizes, int n_in,
                              void* d_out, int out_size, void* d_ws,
                              size_t ws_size, hipStream_t stream) {
  const float* optical = (const float*)d_in[0];
  const float* sar     = (const float*)d_in[1];
  const float* g_opt   = (const float*)d_in[2];
  const float* b_opt   = (const float*)d_in[3];
  const float* g_sar   = (const float*)d_in[4];
  const float* b_sar   = (const float*)d_in[5];
  const float* Wq      = (const float*)d_in[6];
  const float* Wk      = (const float*)d_in[7];
  const float* Wv      = (const float*)d_in[8];
  const float* Wo      = (const float*)d_in[9];
  const float* g_ffn   = (const float*)d_in[10];
  const float* b_ffn   = (const float*)d_in[11];
  const float* W1      = (const float*)d_in[12];
  const float* b1      = (const float*)d_in[13];
  const float* W2      = (const float*)d_in[14];
  const float* b2      = (const float*)d_in[15];

  char* ws = (char*)d_ws;
  bf16* wbf  = (bf16*)ws;
  bf16* Wqb  = wbf;
  bf16* Wkb  = wbf + 65536;
  bf16* WvTb = wbf + 131072;
  bf16* Wob  = wbf + 196608;
  bf16* W1b  = wbf + 262144;   // interleaved, pre-scaled by g_ffn
  bf16* W2b  = wbf + 524288;

  size_t off = 2ull * 1024 * 1024;
  const size_t T16 = 16ull * LSP * CCH * 2;  // 33.5 MB bf16 tensor
  bf16* opt_ncl = (bf16*)(ws + off); off += T16;
  bf16* sar_ncl = (bf16*)(ws + off); off += T16;
  bf16* sar_nlc = (bf16*)(ws + off); off += T16;
  bf16* opt_raw = (bf16*)(ws + off); off += T16;                   // raw bf16
  bf16* xb      = (bf16*)(ws + off); off += T16;                   // x bf16
  float* stats  = (float*)(ws + off); off += 1ull * 1024 * 1024;   // 512KB+
  float* cvec   = (float*)(ws + off); off += 64 * 1024;            // 8KB
  float* Gpart  = (float*)(ws + off); off += 16ull * 1024 * 1024;  // 16 MB
  bf16* G2b     = (bf16*)(ws + off); off += 4ull * 1024 * 1024;
  bf16* UTb     = (bf16*)(ws + off); off += 2ull * 1024 * 1024;
  bf16* Wfoldb  = (bf16*)(ws + off); off += 2ull * 1024 * 1024;

  dim3 blk(256);
  cvt_w_kernel<<<2560, blk, 0, stream>>>(Wq, Wk, Wv, Wo, W1, W2, g_ffn, wbf);
  w1vec_kernel<<<4, blk, 0, stream>>>(W1, b1, g_ffn, b_ffn, cvec);
  ln_tile_kernel<0, 1><<<dim3(64, 16), blk, 0, stream>>>(
      optical, g_opt, b_opt, opt_ncl, nullptr, opt_raw);
  ln_tile_kernel<1, 0><<<dim3(64, 16), blk, 0, stream>>>(
      sar, g_sar, b_sar, sar_ncl, sar_nlc, nullptr);
  gram_kernel<<<dim3(4, 4, 16), blk, 0, stream>>>(sar_ncl, opt_ncl, Gpart);
  greduce_kernel<<<512, blk, 0, stream>>>(Gpart, G2b);
  fold2_kernel<<<128, blk, 0, stream>>>(G2b, Wqb, Wkb, WvTb, UTb);
  wfold_kernel<<<dim3(2, 2, 16), blk, 0, stream>>>(Wob, UTb, Wfoldb);
  xgemm_stats_kernel<<<dim3(64, 16), blk, 0, stream>>>(Wfoldb, sar_nlc,
                                                       opt_raw, xb, stats);
  ffn_fused_kernel<<<dim3(64, 16), dim3(512), 0, stream>>>(
      W1b, W2b, xb, (float*)d_out, cvec, b2, stats);
}

// Round 11
// 252.586 us; speedup vs baseline: 1.1746x; 1.1746x over previous
//
#include <hip/hip_runtime.h>
#include <hip/hip_bf16.h>

typedef __bf16 bf16;
typedef __attribute__((ext_vector_type(8))) __bf16 bf16x8;
typedef __attribute__((ext_vector_type(4))) __bf16 bf16x4;
typedef __attribute__((ext_vector_type(4))) float f32x4;
typedef __attribute__((ext_vector_type(16))) float f32x16;

#define LSP 4096   // H*W
#define CCH 256

__device__ __forceinline__ void gl2lds16(const bf16* g, bf16* l) {
  __builtin_amdgcn_global_load_lds(
      (const __attribute__((address_space(1))) unsigned int*)g,
      (__attribute__((address_space(3))) unsigned int*)l, 16, 0, 0);
}

__device__ __forceinline__ f32x4 mfma16(bf16x8 a, bf16x8 b, f32x4 c) {
  return __builtin_amdgcn_mfma_f32_16x16x32_bf16(a, b, c, 0, 0, 0);
}
__device__ __forceinline__ f32x16 mfma32(bf16x8 a, bf16x8 b, f32x16 c) {
  return __builtin_amdgcn_mfma_f32_32x32x16_bf16(a, b, c, 0, 0, 0);
}

// ---------------------------------------------------------------------------
// Weight f32 -> bf16 (+ fused w1vec in blocks 2560..2563).
// Wq,Wk direct; Wv TRANSPOSED; Wo direct; W1 INTERLEAVED + g_ffn-scaled;
// W2 direct. cvec[0..2047] = per-m folded-LN constants.
// ---------------------------------------------------------------------------
__global__ __launch_bounds__(256) void cvt_w_kernel(
    const float* __restrict__ wq, const float* __restrict__ wk,
    const float* __restrict__ wv, const float* __restrict__ wo,
    const float* __restrict__ w1, const float* __restrict__ w2,
    const float* __restrict__ gff, const float* __restrict__ bff,
    const float* __restrict__ b1, bf16* __restrict__ out,
    float* __restrict__ cvec) {
  if (blockIdx.x >= 2560) {     // w1vec part
    int m = (blockIdx.x - 2560) * 256 + threadIdx.x;   // 0..1023
    const float* row = w1 + (size_t)m * 256;
    float sb = 0.f, sg = 0.f;
    #pragma unroll 8
    for (int c = 0; c < 256; c += 4) {
      f32x4 w = *(const f32x4*)&row[c];
      f32x4 g = *(const f32x4*)&gff[c];
      f32x4 bb = *(const f32x4*)&bff[c];
      #pragma unroll
      for (int j = 0; j < 4; ++j) { sb += w[j] * bb[j]; sg += w[j] * g[j]; }
    }
    if (m < 512) {
      cvec[m] = sb + b1[m];
      cvec[512 + m] = sg;
    } else {
      cvec[512 + m] = sb + b1[m];
      cvec[1024 + m] = sg;
    }
    return;
  }
  int e = blockIdx.x * 256 + threadIdx.x;   // 655360 exact
  if (e < 65536)        { out[e] = (bf16)wq[e]; }
  else if (e < 131072)  { out[e] = (bf16)wk[e - 65536]; }
  else if (e < 196608)  {
    int e2 = e - 131072;            // e2 = och*256 + cin
    int och = e2 >> 8, cin = e2 & 255;
    out[131072 + cin * 256 + och] = (bf16)wv[e2];   // WvT
  }
  else if (e < 262144)  { out[e] = (bf16)wo[e - 196608]; }
  else if (e < 524288)  {
    int e2 = e - 262144;            // m*256 + k
    int m = e2 >> 8, k = e2 & 255;
    int mp = (m < 512) ? (2 * m) : (2 * (m - 512) + 1);
    out[262144 + mp * 256 + k] = (bf16)(w1[e2] * gff[k]);  // W1g interleaved
  }
  else                  { out[e] = (bf16)w2[e - 524288]; }
}

// ---------------------------------------------------------------------------
// Merged tiled LayerNorm: z=0 -> optical (writes cl + RAW lc); z=1 -> sar
// (writes cl + normed lc). Tile 256c x 64l, LDS transpose, XOR swizzle.
// ---------------------------------------------------------------------------
__global__ __launch_bounds__(256) void ln_both_kernel(
    const float* __restrict__ xo, const float* __restrict__ xs,
    const float* __restrict__ g_o, const float* __restrict__ b_o,
    const float* __restrict__ g_s, const float* __restrict__ b_s,
    bf16* __restrict__ opt_cl, bf16* __restrict__ opt_raw,
    bf16* __restrict__ sar_cl, bf16* __restrict__ sar_lc) {
  const int which = blockIdx.z;
  const float* x   = which ? xs : xo;
  const float* gam = which ? g_s : g_o;
  const float* bet = which ? b_s : b_o;
  bf16* out_cl = which ? sar_cl : opt_cl;
  const int l0 = blockIdx.x * 64;
  const int b  = blockIdx.y;
  const int tid = threadIdx.x;
  __shared__ bf16 Tt[256 * 64];          // 32 KB, swizzled
  __shared__ float red[2][16][64];       // 8 KB
  __shared__ float mu_s[64], rs_s[64];

  const float* px = x + (size_t)b * CCH * LSP + l0;
  const int colq = (tid & 15) * 4;
  f32x4 s = {0.f, 0.f, 0.f, 0.f}, q = {0.f, 0.f, 0.f, 0.f};
  #pragma unroll
  for (int it = 0; it < 16; ++it) {
    int c = it * 16 + (tid >> 4);
    f32x4 v = *(const f32x4*)&px[(size_t)c * LSP + colq];
    s += v;
    q += v * v;
    bf16x4 h;
    #pragma unroll
    for (int j = 0; j < 4; ++j) h[j] = (bf16)v[j];
    int colp = colq ^ (((c >> 3) & 7) << 3);
    *(bf16x4*)&Tt[c * 64 + colp] = h;
  }
  #pragma unroll
  for (int j = 0; j < 4; ++j) {
    red[0][tid >> 4][colq + j] = s[j];
    red[1][tid >> 4][colq + j] = q[j];
  }
  __syncthreads();
  if (tid < 64) {
    float S = 0.f, Q = 0.f;
    #pragma unroll
    for (int k = 0; k < 16; ++k) { S += red[0][k][tid]; Q += red[1][k][tid]; }
    float m = S * (1.f / 256.f);
    mu_s[tid] = m;
    rs_s[tid] = rsqrtf(Q * (1.f / 256.f) - m * m + 1e-5f);
  }
  __syncthreads();

  // [c][l] normed output
  #pragma unroll
  for (int it = 0; it < 8; ++it) {
    int ch = it * 256 + tid;
    int c = ch >> 3, col8 = (ch & 7) * 8;
    int colp = col8 ^ (((c >> 3) & 7) << 3);
    bf16x8 h = *(const bf16x8*)&Tt[c * 64 + colp];
    f32x4 m0 = *(const f32x4*)&mu_s[col8];
    f32x4 m1 = *(const f32x4*)&mu_s[col8 + 4];
    f32x4 r0 = *(const f32x4*)&rs_s[col8];
    f32x4 r1 = *(const f32x4*)&rs_s[col8 + 4];
    float g = gam[c], be = bet[c];
    bf16x8 o;
    #pragma unroll
    for (int j = 0; j < 4; ++j) {
      o[j]     = (bf16)(((float)h[j] - m0[j]) * r0[j] * g + be);
      o[4 + j] = (bf16)(((float)h[4 + j] - m1[j]) * r1[j] * g + be);
    }
    *(bf16x8*)&out_cl[((size_t)b * CCH + c) * LSP + l0 + col8] = o;
  }

  if (which == 0) {
    // RAW [l][c] bf16 (residual source downstream)
    #pragma unroll
    for (int it = 0; it < 8; ++it) {
      int ch = it * 256 + tid;
      int l = ch >> 5, cch = ch & 31;
      int c0 = cch * 8;
      int lp = l ^ ((cch & 7) << 3);
      bf16x8 o;
      #pragma unroll
      for (int j = 0; j < 4; ++j) {
        o[j]     = Tt[(c0 + j) * 64 + lp];
        o[4 + j] = Tt[(c0 + 4 + j) * 64 + lp];
      }
      *(bf16x8*)&opt_raw[((size_t)b * LSP + l0 + l) * CCH + c0] = o;
    }
  } else {
    // normed [l][c]
    #pragma unroll
    for (int it = 0; it < 8; ++it) {
      int ch = it * 256 + tid;
      int l = ch >> 5, cch = ch & 31;
      int c0 = cch * 8;
      int lp = l ^ ((cch & 7) << 3);
      float mu = mu_s[l], rs = rs_s[l];
      f32x4 g0 = *(const f32x4*)&gam[c0];
      f32x4 g1 = *(const f32x4*)&gam[c0 + 4];
      f32x4 b0 = *(const f32x4*)&bet[c0];
      f32x4 b1 = *(const f32x4*)&bet[c0 + 4];
      bf16x8 o;
      #pragma unroll
      for (int j = 0; j < 4; ++j) {
        float h0 = (float)Tt[(c0 + j) * 64 + lp];
        float h1 = (float)Tt[(c0 + 4 + j) * 64 + lp];
        o[j]     = (bf16)((h0 - mu) * rs * g0[j] + b0[j]);
        o[4 + j] = (bf16)((h1 - mu) * rs * g1[j] + b1[j]);
      }
      *(bf16x8*)&sar_lc[((size_t)b * LSP + l0 + l) * CCH + c0] = o;
    }
  }
}

// ---------------------------------------------------------------------------
// Gram: 8 l-chunks (512 l each) -> grid (4,8,16) = 512 blocks (2/CU) for
// latency hiding. G2part[chunk][b][j][i].
// ---------------------------------------------------------------------------
__global__ __launch_bounds__(256) void gram_kernel(
    const bf16* __restrict__ sar_cl, const bf16* __restrict__ opt_cl,
    float* __restrict__ part) {
  const int tile = blockIdx.x, chunk = blockIdx.y, b = blockIdx.z;
  const int tid = threadIdx.x, lane = tid & 63, w = tid >> 6;
  const int j0 = (tile >> 1) * 128 + (w >> 1) * 64;
  const int i0 = (tile & 1) * 128 + (w & 1) * 64;
  const int l0 = chunk * 512;
  const bf16* sj = sar_cl + ((size_t)b * CCH + j0 + (lane & 31)) * LSP + l0;
  const bf16* oi = opt_cl + ((size_t)b * CCH + i0 + (lane & 31)) * LSP + l0;
  f32x16 acc[2][2];
  #pragma unroll
  for (int mt = 0; mt < 2; ++mt)
    #pragma unroll
    for (int nt = 0; nt < 2; ++nt)
      #pragma unroll
      for (int r = 0; r < 16; ++r) acc[mt][nt][r] = 0.f;
  #pragma unroll 4
  for (int ks = 0; ks < 32; ++ks) {
    int lofs = ks * 16 + (lane >> 5) * 8;
    bf16x8 a0 = *(const bf16x8*)&sj[lofs];
    bf16x8 a1 = *(const bf16x8*)&sj[32 * LSP + lofs];
    bf16x8 b0 = *(const bf16x8*)&oi[lofs];
    bf16x8 b1 = *(const bf16x8*)&oi[32 * LSP + lofs];
    acc[0][0] = mfma32(a0, b0, acc[0][0]);
    acc[0][1] = mfma32(a0, b1, acc[0][1]);
    acc[1][0] = mfma32(a1, b0, acc[1][0]);
    acc[1][1] = mfma32(a1, b1, acc[1][1]);
  }
  float* op = part + ((size_t)chunk * 16 + b) * 65536;
  #pragma unroll
  for (int mt = 0; mt < 2; ++mt)
    #pragma unroll
    for (int nt = 0; nt < 2; ++nt)
      #pragma unroll
      for (int r = 0; r < 16; ++r) {
        int row = j0 + mt * 32 + (r & 3) + 8 * (r >> 2) + 4 * (lane >> 5);
        int col = i0 + nt * 32 + (lane & 31);
        op[(size_t)row * 256 + col] = acc[mt][nt][r];
      }
}

// ---------------------------------------------------------------------------
// Reduce Gram partials (8 chunks) -> G2 bf16 [b][j][i]
// ---------------------------------------------------------------------------
__global__ __launch_bounds__(256) void greduce_kernel(
    const float* __restrict__ part, bf16* __restrict__ G2) {
  size_t e = ((size_t)blockIdx.x * 256 + threadIdx.x) * 8;  // grid 512
  float a[8];
  #pragma unroll
  for (int i = 0; i < 8; ++i) a[i] = 0.f;
  #pragma unroll
  for (int ch = 0; ch < 8; ++ch) {
    f32x4 p0 = *(const f32x4*)&part[ch * 1048576ull + e];
    f32x4 p1 = *(const f32x4*)&part[ch * 1048576ull + e + 4];
    #pragma unroll
    for (int i = 0; i < 4; ++i) { a[i] += p0[i]; a[4 + i] += p1[i]; }
  }
  bf16x8 o;
  #pragma unroll
  for (int i = 0; i < 8; ++i) o[i] = (bf16)a[i];
  *(bf16x8*)&G2[e] = o;
}

// ---------------------------------------------------------------------------
// Fold: per (b,h): M1[c][j] = sum_i Wq_h[c][i]*G2[j][i],
// S[c][d] = sum_j M1[c][j]*Wk_h[d][j], softmax rows -> P,
// UT[b][cin][h*32+c] = sum_d WvT[cin][h*32+d]*P[c][d].
// ---------------------------------------------------------------------------
__global__ __launch_bounds__(256) void fold2_kernel(
    const bf16* __restrict__ G2, const bf16* __restrict__ Wq,
    const bf16* __restrict__ Wk, const bf16* __restrict__ WvT,
    bf16* __restrict__ UT) {
  const int bh = blockIdx.x;
  const int b = bh >> 3, h = bh & 7;
  const int tid = threadIdx.x, lane = tid & 63, w = tid >> 6;
  __shared__ bf16 M1[32 * 256];
  __shared__ float Sp[4][1024];
  __shared__ float S[1024];
  __shared__ bf16 P[1024];

  const bf16* gq = Wq + (size_t)(h * 32) * 256;
  const bf16* g2b = G2 + (size_t)b * 65536;
  #pragma unroll
  for (int mt = 0; mt < 2; ++mt)
    #pragma unroll
    for (int nt = 0; nt < 4; ++nt) {
      f32x4 acc = {0.f, 0.f, 0.f, 0.f};
      #pragma unroll
      for (int ks = 0; ks < 8; ++ks) {
        bf16x8 a = *(const bf16x8*)&gq[(size_t)(mt * 16 + (lane & 15)) * 256 +
                                       ks * 32 + (lane >> 4) * 8];
        bf16x8 bb = *(const bf16x8*)&g2b[
            (size_t)(w * 64 + nt * 16 + (lane & 15)) * 256 + ks * 32 +
            (lane >> 4) * 8];
        acc = mfma16(a, bb, acc);
      }
      #pragma unroll
      for (int r = 0; r < 4; ++r)
        M1[(mt * 16 + (lane >> 4) * 4 + r) * 256 + w * 64 + nt * 16 +
           (lane & 15)] = (bf16)acc[r];
    }
  __syncthreads();

  const bf16* gk = Wk + (size_t)(h * 32) * 256;
  #pragma unroll
  for (int mt = 0; mt < 2; ++mt)
    #pragma unroll
    for (int dt = 0; dt < 2; ++dt) {
      f32x4 acc = {0.f, 0.f, 0.f, 0.f};
      #pragma unroll
      for (int kk = 0; kk < 2; ++kk) {
        bf16x8 a = *(const bf16x8*)&M1[(mt * 16 + (lane & 15)) * 256 + w * 64 +
                                       kk * 32 + (lane >> 4) * 8];
        bf16x8 bb = *(const bf16x8*)&gk[(size_t)(dt * 16 + (lane & 15)) * 256 +
                                        w * 64 + kk * 32 + (lane >> 4) * 8];
        acc = mfma16(a, bb, acc);
      }
      #pragma unroll
      for (int r = 0; r < 4; ++r)
        Sp[w][(mt * 16 + (lane >> 4) * 4 + r) * 32 + dt * 16 + (lane & 15)] =
            acc[r];
    }
  __syncthreads();
  #pragma unroll
  for (int i = 0; i < 4; ++i) {
    int e = tid + 256 * i;
    S[e] = (Sp[0][e] + Sp[1][e] + Sp[2][e] + Sp[3][e]) * 0.17677669529663687f;
  }
  __syncthreads();
  if (tid < 32) {
    float m = -1e30f;
    #pragma unroll
    for (int d = 0; d < 32; ++d) m = fmaxf(m, S[tid * 32 + d]);
    float sum = 0.f;
    float ex[32];
    #pragma unroll
    for (int d = 0; d < 32; ++d) {
      ex[d] = __expf(S[tid * 32 + d] - m);
      sum += ex[d];
    }
    float inv = 1.f / sum;
    #pragma unroll
    for (int d = 0; d < 32; ++d) P[tid * 32 + d] = (bf16)(ex[d] * inv);
  }
  __syncthreads();

  bf16x8 bfrag[2];
  #pragma unroll
  for (int ct = 0; ct < 2; ++ct)
    bfrag[ct] =
        *(const bf16x8*)&P[(ct * 16 + (lane & 15)) * 32 + (lane >> 4) * 8];
  bf16* outb = UT + (size_t)b * 65536 + h * 32;
  #pragma unroll
  for (int t = 0; t < 4; ++t) {
    int cin16 = w * 64 + t * 16;
    bf16x8 afrag = *(const bf16x8*)&WvT[(size_t)(cin16 + (lane & 15)) * 256 +
                                        h * 32 + (lane >> 4) * 8];
    #pragma unroll
    for (int ct = 0; ct < 2; ++ct) {
      f32x4 acc = {0.f, 0.f, 0.f, 0.f};
      acc = mfma16(afrag, bfrag[ct], acc);
      int c = ct * 16 + (lane & 15);
      int cinr = cin16 + (lane >> 4) * 4;
      #pragma unroll
      for (int r = 0; r < 4; ++r)
        outb[(size_t)(cinr + r) * 256 + c] = (bf16)acc[r];
    }
  }
}

// ---------------------------------------------------------------------------
// Small GEMM for Wfold: out bf16 [b][256][256] = Wo @ UT   (128x128 tiles)
// ---------------------------------------------------------------------------
__global__ __launch_bounds__(256) void wfold_kernel(
    const bf16* __restrict__ Aw, const bf16* __restrict__ Bx,
    bf16* __restrict__ outp) {
  const int tid = threadIdx.x;
  const int lane = tid & 63;
  const int wave = tid >> 6;
  const int wr = wave >> 1, wc = wave & 1;
  const int l0 = blockIdx.x * 128;
  const int m0 = blockIdx.y * 128;
  const int b  = blockIdx.z;
  constexpr int NB = 4096;
  __shared__ bf16 smem[4 * NB];
  bf16* As = smem;
  bf16* Bs = smem + 2 * NB;
  const bf16* Ag = Aw + (size_t)m0 * 256;
  const bf16* Bg = Bx + ((size_t)b * 256 + l0) * 256;
  auto stage = [&](int buf, int k0) {
    #pragma unroll
    for (int i = 0; i < 2; ++i) {
      int ch = i * 256 + tid;
      int r  = ch >> 2;
      int c8 = (ch & 3) * 8;
      gl2lds16(Ag + (size_t)r * 256 + k0 + c8, As + buf * NB + ch * 8);
      gl2lds16(Bg + (size_t)r * 256 + k0 + c8, Bs + buf * NB + ch * 8);
    }
  };
  f32x4 acc[4][4];
  #pragma unroll
  for (int mi = 0; mi < 4; ++mi)
    #pragma unroll
    for (int ni = 0; ni < 4; ++ni)
      #pragma unroll
      for (int r = 0; r < 4; ++r) acc[mi][ni][r] = 0.f;
  stage(0, 0);
  for (int kt = 0; kt < 8; ++kt) {
    __syncthreads();
    if (kt + 1 < 8) stage((kt + 1) & 1, (kt + 1) * 32);
    const bf16* Ab = As + (kt & 1) * NB;
    const bf16* Bb = Bs + (kt & 1) * NB;
    bf16x8 af[4], bfr[4];
    #pragma unroll
    for (int mi = 0; mi < 4; ++mi)
      af[mi] = *(const bf16x8*)&Ab[(wr * 64 + mi * 16 + (lane & 15)) * 32 +
                                   (lane >> 4) * 8];
    #pragma unroll
    for (int ni = 0; ni < 4; ++ni)
      bfr[ni] = *(const bf16x8*)&Bb[(wc * 64 + ni * 16 + (lane & 15)) * 32 +
                                    (lane >> 4) * 8];
    #pragma unroll
    for (int mi = 0; mi < 4; ++mi)
      #pragma unroll
      for (int ni = 0; ni < 4; ++ni)
        acc[mi][ni] = mfma16(af[mi], bfr[ni], acc[mi][ni]);
  }
  const int mq = m0 + wr * 64 + (lane >> 4) * 4;
  const int lq = l0 + wc * 64 + (lane & 15);
  #pragma unroll
  for (int mi = 0; mi < 4; ++mi)
    #pragma unroll
    for (int ni = 0; ni < 4; ++ni) {
      int l = lq + ni * 16, mb = mq + mi * 16;
      #pragma unroll
      for (int r = 0; r < 4; ++r)
        outp[((size_t)b * 256 + mb + r) * 256 + l] = (bf16)acc[mi][ni][r];
    }
}

// ---------------------------------------------------------------------------
// Fused x-GEMM + residual + LN-stats (M=256, N=64, K=256).
// Residual from RAW bf16 optical [b][l][c] (L3-hot, coalesced).
// ---------------------------------------------------------------------------
__global__ __launch_bounds__(256) void xgemm_stats_kernel(
    const bf16* __restrict__ Wfold, const bf16* __restrict__ sar_lc,
    const bf16* __restrict__ opt_raw, bf16* __restrict__ xout,
    float* __restrict__ stats) {
  const int tid = threadIdx.x, lane = tid & 63, w = tid >> 6;
  const int l0 = blockIdx.x * 64;
  const int b  = blockIdx.y;
  __shared__ __align__(16) char smem[43520];
  bf16* X = (bf16*)smem;
  float* red = (float*)(smem + 40960);

  const bf16* Ag = Wfold + (size_t)b * 65536;
  const bf16* Bg = sar_lc + ((size_t)b * LSP + l0) * CCH;

  auto stage = [&](int buf, int k0) {
    bf16* As = (bf16*)(smem + buf * 16384);
    bf16* Bs = (bf16*)(smem + 32768 + buf * 4096);
    #pragma unroll
    for (int i = 0; i < 4; ++i) {
      int ch = i * 256 + tid;
      int r = ch >> 2, c8 = (ch & 3) * 8;
      gl2lds16(Ag + (size_t)r * 256 + k0 + c8, &As[ch * 8]);
    }
    {
      int r = tid >> 2, c8 = (tid & 3) * 8;
      gl2lds16(Bg + (size_t)r * 256 + k0 + c8, &Bs[tid * 8]);
    }
  };

  f32x4 acc[4][4];
  #pragma unroll
  for (int mi = 0; mi < 4; ++mi)
    #pragma unroll
    for (int ni = 0; ni < 4; ++ni)
      #pragma unroll
      for (int r = 0; r < 4; ++r) acc[mi][ni][r] = 0.f;

  stage(0, 0);
  for (int kt = 0; kt < 8; ++kt) {
    __syncthreads();
    if (kt < 7) stage((kt + 1) & 1, (kt + 1) * 32);
    const bf16* Ab = (const bf16*)(smem + (kt & 1) * 16384);
    const bf16* Bb = (const bf16*)(smem + 32768 + (kt & 1) * 4096);
    bf16x8 af[4], bfr[4];
    #pragma unroll
    for (int mi = 0; mi < 4; ++mi)
      af[mi] = *(const bf16x8*)&Ab[(w * 64 + mi * 16 + (lane & 15)) * 32 +
                                   (lane >> 4) * 8];
    #pragma unroll
    for (int ni = 0; ni < 4; ++ni)
      bfr[ni] = *(const bf16x8*)&Bb[(ni * 16 + (lane & 15)) * 32 +
                                    (lane >> 4) * 8];
    #pragma unroll
    for (int mi = 0; mi < 4; ++mi)
      #pragma unroll
      for (int ni = 0; ni < 4; ++ni)
        acc[mi][ni] = mfma16(af[mi], bfr[ni], acc[mi][ni]);
  }
  __syncthreads();   // all LDS frag reads done; As/Bs region reused as X

  const int cb = w * 64 + (lane >> 4) * 4;
  const int lb = lane & 15;
  float s[4], q[4];
  #pragma unroll
  for (int ni = 0; ni < 4; ++ni) { s[ni] = 0.f; q[ni] = 0.f; }
  #pragma unroll
  for (int mi = 0; mi < 4; ++mi)
    #pragma unroll
    for (int ni = 0; ni < 4; ++ni) {
      int c = cb + mi * 16, ll = lb + ni * 16;
      bf16x4 o4 = *(const bf16x4*)&opt_raw[((size_t)b * LSP + l0 + ll) * CCH + c];
      bf16x4 hx;
      #pragma unroll
      for (int r = 0; r < 4; ++r) {
        float v = acc[mi][ni][r] + (float)o4[r];
        s[ni] += v; q[ni] += v * v;
        hx[r] = (bf16)v;
      }
      *(bf16x4*)&X[ll * 260 + c] = hx;
    }
  #pragma unroll
  for (int ni = 0; ni < 4; ++ni) {
    s[ni] += __shfl_xor(s[ni], 16);
    s[ni] += __shfl_xor(s[ni], 32);
    q[ni] += __shfl_xor(q[ni], 16);
    q[ni] += __shfl_xor(q[ni], 32);
  }
  if ((lane >> 4) == 0) {
    #pragma unroll
    for (int ni = 0; ni < 4; ++ni) {
      red[(0 * 4 + w) * 64 + ni * 16 + lb] = s[ni];
      red[(4 + w) * 64 + ni * 16 + lb] = q[ni];
    }
  }
  __syncthreads();
  if (tid < 64) {
    float S4 = red[0 * 64 + tid] + red[1 * 64 + tid] + red[2 * 64 + tid] +
               red[3 * 64 + tid];
    float Q4 = red[4 * 64 + tid] + red[5 * 64 + tid] + red[6 * 64 + tid] +
               red[7 * 64 + tid];
    float m = S4 * (1.f / 256.f);
    float rs = rsqrtf(Q4 * (1.f / 256.f) - m * m + 1e-5f);
    float* st = stats + ((size_t)b * LSP + l0 + tid) * 2;
    st[0] = m;
    st[1] = rs;
  }
  __syncthreads();
  #pragma unroll
  for (int it = 0; it < 8; ++it) {
    int cid = it * 256 + tid;            // 2048 chunks of 16B
    int l = cid >> 5, c0 = (cid & 31) * 8;
    bf16x8 v = *(const bf16x8*)&X[l * 260 + c0];
    *(bf16x8*)&xout[((size_t)b * LSP + l0 + l) * CCH + c0] = v;
  }
}

// ---------------------------------------------------------------------------
// 256x256-tile 8-phase GEMM, gray-code quadrant order with B register-cached
// (R8 proven: 51.6 us each). MODE 0 (KEL=256): A = W1g interleaved ->
// folded-LN + SimpleGate, bf16 [b][l][512]. MODE 1 (KEL=512): A = W2 ->
// + b2 + res(bf16 x), f32 d_out [b][c][l].
// ---------------------------------------------------------------------------
template <int KEL, int MODE>
__global__ __launch_bounds__(512, 2) void ffn_gemm_kernel(
    const bf16* __restrict__ Aw, const bf16* __restrict__ Bx,
    void* __restrict__ outp, const bf16* __restrict__ resb,
    const float* __restrict__ bias, const float* __restrict__ stats) {
  constexpr int LDSB = (MODE == 1) ? 135168 : 131072;
  __shared__ __align__(16) char smem_raw[LDSB];
  const int tid = threadIdx.x;
  const int lane = tid & 63;
  const int wave = tid >> 6;
  const int wr = wave >> 2;        // 0..1  (m half: 128 rows)
  const int wc = wave & 3;         // 0..3  (n quarter: 64 cols)
  const int l0 = blockIdx.x * 256;
  const int m0 = blockIdx.y * 256;
  const int b  = blockIdx.z;

  char* ldsA0 = smem_raw;                  // A tile buf0: 256x64 bf16 = 32KB
  char* ldsB0 = smem_raw + 32768;
  char* ldsA1 = smem_raw + 65536;
  char* ldsB1 = smem_raw + 98304;

  const bf16* Ag = Aw + (size_t)m0 * KEL;
  const bf16* Bg = Bx + ((size_t)b * LSP + l0) * KEL;

  auto STAGE = [&](const bf16* gsrc, char* ldst, int par, int kt) {
    #pragma unroll
    for (int i = 0; i < 2; ++i) {
      int qi = i * 512 + tid;                       // 0..1023 chunk-in-half
      int r  = ((qi >> 7) << 5) + (par << 4) + ((qi >> 3) & 15);
      int cl = (qi & 7) ^ ((qi >> 3) & 7);          // pre-swizzled source col
      int p  = ((qi >> 7) << 8) + (par << 7) + (qi & 127);  // linear dest
      gl2lds16(gsrc + (size_t)r * KEL + kt * 64 + cl * 8,
               (bf16*)(ldst + p * 16));
    }
  };

  f32x4 acc[8][4];
  #pragma unroll
  for (int mi = 0; mi < 8; ++mi)
    #pragma unroll
    for (int ni = 0; ni < 4; ++ni)
      #pragma unroll
      for (int r = 0; r < 4; ++r) acc[mi][ni][r] = 0.f;

  bf16x8 af[4][2], bn0[2][2], bn1[2][2];
  const int col0 = (((lane >> 4) << 4)) ^ ((lane & 7) << 4);
  const int col1 = col0 ^ 64;
  const int arow_off = (lane & 15) * 128;

#define LOAD_A(BUFA, MP)                                                      \
  {                                                                           \
    const char* Ab_ = (BUFA);                                                 \
    _Pragma("unroll") for (int j = 0; j < 4; ++j) {                           \
      int rb = (wr * 128 + ((MP) + 2 * j) * 16) * 128 + arow_off;             \
      af[j][0] = *(const bf16x8*)(Ab_ + rb + col0);                           \
      af[j][1] = *(const bf16x8*)(Ab_ + rb + col1);                           \
    }                                                                         \
  }

#define LOAD_B(BUFB, NP, DST)                                                 \
  {                                                                           \
    const char* Bb_ = (BUFB);                                                 \
    _Pragma("unroll") for (int i = 0; i < 2; ++i) {                           \
      int rb = (wc * 64 + ((NP) + 2 * i) * 16) * 128 + arow_off;              \
      DST[i][0] = *(const bf16x8*)(Bb_ + rb + col0);                          \
      DST[i][1] = *(const bf16x8*)(Bb_ + rb + col1);                          \
    }                                                                         \
  }

#define DO_MFMA(MP, NP, BS)                                                   \
  _Pragma("unroll") for (int j = 0; j < 4; ++j)                               \
  _Pragma("unroll") for (int i = 0; i < 2; ++i) {                             \
    acc[(MP) + 2 * j][(NP) + 2 * i] =                                         \
        mfma16(af[j][0], BS[i][0], acc[(MP) + 2 * j][(NP) + 2 * i]);          \
    acc[(MP) + 2 * j][(NP) + 2 * i] =                                         \
        mfma16(af[j][1], BS[i][1], acc[(MP) + 2 * j][(NP) + 2 * i]);          \
  }

#define PH_HEAD                                                               \
  asm volatile("s_waitcnt vmcnt(6)" ::: "memory");                            \
  __builtin_amdgcn_s_barrier();                                               \
  __builtin_amdgcn_sched_barrier(0);

#define PH_TAIL(MP, NP, BS)                                                   \
  asm volatile("s_waitcnt lgkmcnt(0)" ::: "memory");                          \
  __builtin_amdgcn_sched_barrier(0);                                         \
  __builtin_amdgcn_s_setprio(1);                                              \
  DO_MFMA(MP, NP, BS);                                                        \
  __builtin_amdgcn_s_setprio(0);

  STAGE(Ag, ldsA0, 0, 0);
  STAGE(Bg, ldsB0, 0, 0);
  STAGE(Bg, ldsB0, 1, 0);
  STAGE(Ag, ldsA0, 1, 0);
  STAGE(Ag, ldsA1, 0, 1);
  STAGE(Bg, ldsB1, 1, 1);

  constexpr int NITER = KEL / 128;
  constexpr int KMAX = KEL / 64 - 1;
  for (int t = 0; t < NITER; ++t) {
    const int k1 = 2 * t + 1;
    const int k2 = (2 * t + 2 > KMAX) ? KMAX : 2 * t + 2;
    const int k3 = (2 * t + 3 > KMAX) ? KMAX : 2 * t + 3;
    // ph1 (0,0) buf0
    PH_HEAD; LOAD_A(ldsA0, 0); LOAD_B(ldsB0, 0, bn0);
    STAGE(Bg, ldsB1, 0, k1); STAGE(Ag, ldsA1, 1, k1);
    PH_TAIL(0, 0, bn0);
    // ph2 (0,1)
    PH_HEAD; LOAD_B(ldsB0, 1, bn1);
    PH_TAIL(0, 1, bn1);
    // ph3 (1,1)
    PH_HEAD; LOAD_A(ldsA0, 1); STAGE(Ag, ldsA0, 0, k2);
    PH_TAIL(1, 1, bn1);
    // ph4 (1,0)
    PH_HEAD; STAGE(Bg, ldsB0, 1, k2);
    PH_TAIL(1, 0, bn0);
    // ph5 (0,0) buf1
    PH_HEAD; LOAD_A(ldsA1, 0); LOAD_B(ldsB1, 0, bn0);
    STAGE(Bg, ldsB0, 0, k2);
    PH_TAIL(0, 0, bn0);
    // ph6 (0,1)
    PH_HEAD; LOAD_B(ldsB1, 1, bn1); STAGE(Ag, ldsA0, 1, k2);
    PH_TAIL(0, 1, bn1);
    // ph7 (1,1)
    PH_HEAD; LOAD_A(ldsA1, 1); STAGE(Ag, ldsA1, 0, k3);
    PH_TAIL(1, 1, bn1);
    // ph8 (1,0)
    PH_HEAD; STAGE(Bg, ldsB1, 1, k3);
    PH_TAIL(1, 0, bn0);
  }
#undef PH_HEAD
#undef PH_TAIL
#undef DO_MFMA
#undef LOAD_A
#undef LOAD_B

  asm volatile("s_waitcnt vmcnt(0)" ::: "memory");
  __syncthreads();

  if constexpr (MODE == 0) {
    // folded-LN + SimpleGate epilogue
    bf16* g_lds = (bf16*)smem_raw;           // [256 l][136 pad] bf16 = 68KB
    const int lq = wc * 64 + (lane & 15);
    const int qq = (lane >> 4);
    const float* stb = stats + ((size_t)b * LSP + l0) * 2;
    float muv[4], rsv[4];
    #pragma unroll
    for (int ni = 0; ni < 4; ++ni) {
      int l = lq + ni * 16;
      muv[ni] = stb[l * 2];
      rsv[ni] = stb[l * 2 + 1];
    }
    #pragma unroll
    for (int mi = 0; mi < 8; ++mi) {
      int a0 = wr * 64 + mi * 8 + qq * 2;    // local gate row (0..127)
      int ag = (m0 >> 1) + a0;               // global gate row (0..511)
      float be1a = bias[ag],        ga1a = bias[512 + ag];
      float be2a = bias[1024 + ag], ga2a = bias[1536 + ag];
      float be1b = bias[ag + 1],        ga1b = bias[512 + ag + 1];
      float be2b = bias[1024 + ag + 1], ga2b = bias[1536 + ag + 1];
      #pragma unroll
      for (int ni = 0; ni < 4; ++ni) {
        int l = lq + ni * 16;
        float mrs = muv[ni] * rsv[ni];
        float h1a = rsv[ni] * acc[mi][ni][0] + be1a - mrs * ga1a;
        float h2a = rsv[ni] * acc[mi][ni][1] + be2a - mrs * ga2a;
        float h1b = rsv[ni] * acc[mi][ni][2] + be1b - mrs * ga1b;
        float h2b = rsv[ni] * acc[mi][ni][3] + be2b - mrs * ga2b;
        bf16 gv0 = (bf16)(h1a * h2a), gv1 = (bf16)(h1b * h2b);
        unsigned u = ((unsigned)*(unsigned short*)&gv1 << 16) |
                     (unsigned)*(unsigned short*)&gv0;
        *(unsigned*)&g_lds[l * 136 + a0] = u;
      }
    }
    __syncthreads();
    bf16* out = (bf16*)outp;
    const int gy = blockIdx.y * 128;
    #pragma unroll
    for (int it = 0; it < 8; ++it) {
      int cid = it * 512 + tid;              // 4096 chunks of 16B
      int l = cid >> 4, ch = cid & 15;
      bf16x8 v = *(const bf16x8*)&g_lds[l * 136 + ch * 8];
      *(bf16x8*)&out[((size_t)b * LSP + l0 + l) * 512 + gy + ch * 8] = v;
    }
  } else {
    float* lds_f = (float*)smem_raw;         // [128 c][260 pad] f32 = 133KB
    float* out = (float*)outp;
    const int lq = wc * 64 + (lane & 15);
    const int qq = (lane >> 4);
    #pragma unroll
    for (int round = 0; round < 2; ++round) {
      if (wr == round) {
        #pragma unroll
        for (int mi = 0; mi < 8; ++mi) {
          int c0 = mi * 16 + qq * 4;         // local c (0..127)
          f32x4 b4 = *(const f32x4*)&bias[round * 128 + c0];
          #pragma unroll
          for (int ni = 0; ni < 4; ++ni) {
            int l = lq + ni * 16;
            bf16x4 xr4 = *(const bf16x4*)&resb[((size_t)b * LSP + l0 + l) *
                                                   CCH + round * 128 + c0];
            #pragma unroll
            for (int r = 0; r < 4; ++r)
              lds_f[(c0 + r) * 260 + l] =
                  acc[mi][ni][r] + b4[r] + (float)xr4[r];
          }
        }
      }
      __syncthreads();
      #pragma unroll
      for (int it = 0; it < 16; ++it) {
        int cid = it * 512 + tid;            // 8192 chunks of 16B
        int c = cid >> 6, lch = cid & 63;
        f32x4 v = *(const f32x4*)&lds_f[c * 260 + lch * 4];
        *(f32x4*)&out[((size_t)b * CCH + round * 128 + c) * LSP + l0 +
                      lch * 4] = v;
      }
      __syncthreads();
    }
  }
}

// ---------------------------------------------------------------------------
extern "C" void kernel_launch(void* const* d_in, const int* in_sizes, int n_in,
                              void* d_out, int out_size, void* d_ws,
                              size_t ws_size, hipStream_t stream) {
  const float* optical = (const float*)d_in[0];
  const float* sar     = (const float*)d_in[1];
  const float* g_opt   = (const float*)d_in[2];
  const float* b_opt   = (const float*)d_in[3];
  const float* g_sar   = (const float*)d_in[4];
  const float* b_sar   = (const float*)d_in[5];
  const float* Wq      = (const float*)d_in[6];
  const float* Wk      = (const float*)d_in[7];
  const float* Wv      = (const float*)d_in[8];
  const float* Wo      = (const float*)d_in[9];
  const float* g_ffn   = (const float*)d_in[10];
  const float* b_ffn   = (const float*)d_in[11];
  const float* W1      = (const float*)d_in[12];
  const float* b1      = (const float*)d_in[13];
  const float* W2      = (const float*)d_in[14];
  const float* b2      = (const float*)d_in[15];

  char* ws = (char*)d_ws;
  bf16* wbf  = (bf16*)ws;
  bf16* Wqb  = wbf;
  bf16* Wkb  = wbf + 65536;
  bf16* WvTb = wbf + 131072;
  bf16* Wob  = wbf + 196608;
  bf16* W1b  = wbf + 262144;   // interleaved, pre-scaled by g_ffn
  bf16* W2b  = wbf + 524288;

  size_t off = 2ull * 1024 * 1024;
  const size_t T16 = 16ull * LSP * CCH * 2;  // 33.5 MB bf16 tensor
  bf16* opt_ncl = (bf16*)(ws + off); off += T16;
  bf16* sar_ncl = (bf16*)(ws + off); off += T16;
  bf16* sar_nlc = (bf16*)(ws + off); off += T16;
  bf16* opt_raw = (bf16*)(ws + off); off += T16;                   // raw bf16
  bf16* xb      = (bf16*)(ws + off); off += T16;                   // x bf16
  float* stats  = (float*)(ws + off); off += 1ull * 1024 * 1024;   // 512KB+
  float* cvec   = (float*)(ws + off); off += 64 * 1024;            // 8KB
  float* Gpart  = (float*)(ws + off); off += 34ull * 1024 * 1024;  // 33.5 MB
  bf16* G2b     = (bf16*)(ws + off); off += 4ull * 1024 * 1024;
  bf16* UTb     = (bf16*)(ws + off); off += 2ull * 1024 * 1024;
  bf16* Wfoldb  = (bf16*)(ws + off); off += 2ull * 1024 * 1024;
  bf16* gbuf = opt_ncl;  // 67 MB overlay (opt_ncl+sar_ncl dead after gram)

  dim3 blk(256);
  cvt_w_kernel<<<2564, blk, 0, stream>>>(Wq, Wk, Wv, Wo, W1, W2, g_ffn, b_ffn,
                                         b1, wbf, cvec);
  ln_both_kernel<<<dim3(64, 16, 2), blk, 0, stream>>>(
      optical, sar, g_opt, b_opt, g_sar, b_sar, opt_ncl, opt_raw, sar_ncl,
      sar_nlc);
  gram_kernel<<<dim3(4, 8, 16), blk, 0, stream>>>(sar_ncl, opt_ncl, Gpart);
  greduce_kernel<<<512, blk, 0, stream>>>(Gpart, G2b);
  fold2_kernel<<<128, blk, 0, stream>>>(G2b, Wqb, Wkb, WvTb, UTb);
  wfold_kernel<<<dim3(2, 2, 16), blk, 0, stream>>>(Wob, UTb, Wfoldb);
  xgemm_stats_kernel<<<dim3(64, 16), blk, 0, stream>>>(Wfoldb, sar_nlc,
                                                       opt_raw, xb, stats);
  ffn_gemm_kernel<256, 0><<<dim3(16, 4, 16), dim3(512), 0, stream>>>(
      W1b, xb, gbuf, nullptr, cvec, stats);
  ffn_gemm_kernel<512, 1><<<dim3(16, 1, 16), dim3(512), 0, stream>>>(
      W2b, gbuf, (float*)d_out, xb, b2, nullptr);
}

// Round 12
// 252.511 us; speedup vs baseline: 1.1749x; 1.0003x over previous
//
#include <hip/hip_runtime.h>
#include <hip/hip_bf16.h>

typedef __bf16 bf16;
typedef __attribute__((ext_vector_type(8))) __bf16 bf16x8;
typedef __attribute__((ext_vector_type(4))) __bf16 bf16x4;
typedef __attribute__((ext_vector_type(4))) float f32x4;
typedef __attribute__((ext_vector_type(16))) float f32x16;

#define LSP 4096   // H*W
#define CCH 256

__device__ __forceinline__ void gl2lds16(const bf16* g, bf16* l) {
  __builtin_amdgcn_global_load_lds(
      (const __attribute__((address_space(1))) unsigned int*)g,
      (__attribute__((address_space(3))) unsigned int*)l, 16, 0, 0);
}

__device__ __forceinline__ f32x4 mfma16(bf16x8 a, bf16x8 b, f32x4 c) {
  return __builtin_amdgcn_mfma_f32_16x16x32_bf16(a, b, c, 0, 0, 0);
}
__device__ __forceinline__ f32x16 mfma32(bf16x8 a, bf16x8 b, f32x16 c) {
  return __builtin_amdgcn_mfma_f32_32x32x16_bf16(a, b, c, 0, 0, 0);
}

// ---------------------------------------------------------------------------
// Weight f32 -> bf16 (+ fused w1vec in blocks 2560..2563).
// ---------------------------------------------------------------------------
__global__ __launch_bounds__(256) void cvt_w_kernel(
    const float* __restrict__ wq, const float* __restrict__ wk,
    const float* __restrict__ wv, const float* __restrict__ wo,
    const float* __restrict__ w1, const float* __restrict__ w2,
    const float* __restrict__ gff, const float* __restrict__ bff,
    const float* __restrict__ b1, bf16* __restrict__ out,
    float* __restrict__ cvec) {
  if (blockIdx.x >= 2560) {     // w1vec part
    int m = (blockIdx.x - 2560) * 256 + threadIdx.x;   // 0..1023
    const float* row = w1 + (size_t)m * 256;
    float sb = 0.f, sg = 0.f;
    #pragma unroll 8
    for (int c = 0; c < 256; c += 4) {
      f32x4 w = *(const f32x4*)&row[c];
      f32x4 g = *(const f32x4*)&gff[c];
      f32x4 bb = *(const f32x4*)&bff[c];
      #pragma unroll
      for (int j = 0; j < 4; ++j) { sb += w[j] * bb[j]; sg += w[j] * g[j]; }
    }
    if (m < 512) {
      cvec[m] = sb + b1[m];
      cvec[512 + m] = sg;
    } else {
      cvec[512 + m] = sb + b1[m];
      cvec[1024 + m] = sg;
    }
    return;
  }
  int e = blockIdx.x * 256 + threadIdx.x;   // 655360 exact
  if (e < 65536)        { out[e] = (bf16)wq[e]; }
  else if (e < 131072)  { out[e] = (bf16)wk[e - 65536]; }
  else if (e < 196608)  {
    int e2 = e - 131072;            // e2 = och*256 + cin
    int och = e2 >> 8, cin = e2 & 255;
    out[131072 + cin * 256 + och] = (bf16)wv[e2];   // WvT
  }
  else if (e < 262144)  { out[e] = (bf16)wo[e - 196608]; }
  else if (e < 524288)  {
    int e2 = e - 262144;            // m*256 + k
    int m = e2 >> 8, k = e2 & 255;
    int mp = (m < 512) ? (2 * m) : (2 * (m - 512) + 1);
    out[262144 + mp * 256 + k] = (bf16)(w1[e2] * gff[k]);  // W1g interleaved
  }
  else                  { out[e] = (bf16)w2[e - 524288]; }
}

// ---------------------------------------------------------------------------
// Merged tiled LayerNorm: z=0 -> optical (writes cl + RAW lc); z=1 -> sar
// (writes cl + normed lc).
// ---------------------------------------------------------------------------
__global__ __launch_bounds__(256) void ln_both_kernel(
    const float* __restrict__ xo, const float* __restrict__ xs,
    const float* __restrict__ g_o, const float* __restrict__ b_o,
    const float* __restrict__ g_s, const float* __restrict__ b_s,
    bf16* __restrict__ opt_cl, bf16* __restrict__ opt_raw,
    bf16* __restrict__ sar_cl, bf16* __restrict__ sar_lc) {
  const int which = blockIdx.z;
  const float* x   = which ? xs : xo;
  const float* gam = which ? g_s : g_o;
  const float* bet = which ? b_s : b_o;
  bf16* out_cl = which ? sar_cl : opt_cl;
  const int l0 = blockIdx.x * 64;
  const int b  = blockIdx.y;
  const int tid = threadIdx.x;
  __shared__ bf16 Tt[256 * 64];          // 32 KB, swizzled
  __shared__ float red[2][16][64];       // 8 KB
  __shared__ float mu_s[64], rs_s[64];

  const float* px = x + (size_t)b * CCH * LSP + l0;
  const int colq = (tid & 15) * 4;
  f32x4 s = {0.f, 0.f, 0.f, 0.f}, q = {0.f, 0.f, 0.f, 0.f};
  #pragma unroll
  for (int it = 0; it < 16; ++it) {
    int c = it * 16 + (tid >> 4);
    f32x4 v = *(const f32x4*)&px[(size_t)c * LSP + colq];
    s += v;
    q += v * v;
    bf16x4 h;
    #pragma unroll
    for (int j = 0; j < 4; ++j) h[j] = (bf16)v[j];
    int colp = colq ^ (((c >> 3) & 7) << 3);
    *(bf16x4*)&Tt[c * 64 + colp] = h;
  }
  #pragma unroll
  for (int j = 0; j < 4; ++j) {
    red[0][tid >> 4][colq + j] = s[j];
    red[1][tid >> 4][colq + j] = q[j];
  }
  __syncthreads();
  if (tid < 64) {
    float S = 0.f, Q = 0.f;
    #pragma unroll
    for (int k = 0; k < 16; ++k) { S += red[0][k][tid]; Q += red[1][k][tid]; }
    float m = S * (1.f / 256.f);
    mu_s[tid] = m;
    rs_s[tid] = rsqrtf(Q * (1.f / 256.f) - m * m + 1e-5f);
  }
  __syncthreads();

  // [c][l] normed output
  #pragma unroll
  for (int it = 0; it < 8; ++it) {
    int ch = it * 256 + tid;
    int c = ch >> 3, col8 = (ch & 7) * 8;
    int colp = col8 ^ (((c >> 3) & 7) << 3);
    bf16x8 h = *(const bf16x8*)&Tt[c * 64 + colp];
    f32x4 m0 = *(const f32x4*)&mu_s[col8];
    f32x4 m1 = *(const f32x4*)&mu_s[col8 + 4];
    f32x4 r0 = *(const f32x4*)&rs_s[col8];
    f32x4 r1 = *(const f32x4*)&rs_s[col8 + 4];
    float g = gam[c], be = bet[c];
    bf16x8 o;
    #pragma unroll
    for (int j = 0; j < 4; ++j) {
      o[j]     = (bf16)(((float)h[j] - m0[j]) * r0[j] * g + be);
      o[4 + j] = (bf16)(((float)h[4 + j] - m1[j]) * r1[j] * g + be);
    }
    *(bf16x8*)&out_cl[((size_t)b * CCH + c) * LSP + l0 + col8] = o;
  }

  if (which == 0) {
    // RAW [l][c] bf16 (residual source downstream)
    #pragma unroll
    for (int it = 0; it < 8; ++it) {
      int ch = it * 256 + tid;
      int l = ch >> 5, cch = ch & 31;
      int c0 = cch * 8;
      int lp = l ^ ((cch & 7) << 3);
      bf16x8 o;
      #pragma unroll
      for (int j = 0; j < 4; ++j) {
        o[j]     = Tt[(c0 + j) * 64 + lp];
        o[4 + j] = Tt[(c0 + 4 + j) * 64 + lp];
      }
      *(bf16x8*)&opt_raw[((size_t)b * LSP + l0 + l) * CCH + c0] = o;
    }
  } else {
    // normed [l][c]
    #pragma unroll
    for (int it = 0; it < 8; ++it) {
      int ch = it * 256 + tid;
      int l = ch >> 5, cch = ch & 31;
      int c0 = cch * 8;
      int lp = l ^ ((cch & 7) << 3);
      float mu = mu_s[l], rs = rs_s[l];
      f32x4 g0 = *(const f32x4*)&gam[c0];
      f32x4 g1 = *(const f32x4*)&gam[c0 + 4];
      f32x4 b0 = *(const f32x4*)&bet[c0];
      f32x4 b1 = *(const f32x4*)&bet[c0 + 4];
      bf16x8 o;
      #pragma unroll
      for (int j = 0; j < 4; ++j) {
        float h0 = (float)Tt[(c0 + j) * 64 + lp];
        float h1 = (float)Tt[(c0 + 4 + j) * 64 + lp];
        o[j]     = (bf16)((h0 - mu) * rs * g0[j] + b0[j]);
        o[4 + j] = (bf16)((h1 - mu) * rs * g1[j] + b1[j]);
      }
      *(bf16x8*)&sar_lc[((size_t)b * LSP + l0 + l) * CCH + c0] = o;
    }
  }
}

// ---------------------------------------------------------------------------
// Gram: 8 l-chunks (512 l each) -> grid (4,8,16) = 512 blocks.
// ---------------------------------------------------------------------------
__global__ __launch_bounds__(256) void gram_kernel(
    const bf16* __restrict__ sar_cl, const bf16* __restrict__ opt_cl,
    float* __restrict__ part) {
  const int tile = blockIdx.x, chunk = blockIdx.y, b = blockIdx.z;
  const int tid = threadIdx.x, lane = tid & 63, w = tid >> 6;
  const int j0 = (tile >> 1) * 128 + (w >> 1) * 64;
  const int i0 = (tile & 1) * 128 + (w & 1) * 64;
  const int l0 = chunk * 512;
  const bf16* sj = sar_cl + ((size_t)b * CCH + j0 + (lane & 31)) * LSP + l0;
  const bf16* oi = opt_cl + ((size_t)b * CCH + i0 + (lane & 31)) * LSP + l0;
  f32x16 acc[2][2];
  #pragma unroll
  for (int mt = 0; mt < 2; ++mt)
    #pragma unroll
    for (int nt = 0; nt < 2; ++nt)
      #pragma unroll
      for (int r = 0; r < 16; ++r) acc[mt][nt][r] = 0.f;
  #pragma unroll 4
  for (int ks = 0; ks < 32; ++ks) {
    int lofs = ks * 16 + (lane >> 5) * 8;
    bf16x8 a0 = *(const bf16x8*)&sj[lofs];
    bf16x8 a1 = *(const bf16x8*)&sj[32 * LSP + lofs];
    bf16x8 b0 = *(const bf16x8*)&oi[lofs];
    bf16x8 b1 = *(const bf16x8*)&oi[32 * LSP + lofs];
    acc[0][0] = mfma32(a0, b0, acc[0][0]);
    acc[0][1] = mfma32(a0, b1, acc[0][1]);
    acc[1][0] = mfma32(a1, b0, acc[1][0]);
    acc[1][1] = mfma32(a1, b1, acc[1][1]);
  }
  float* op = part + ((size_t)chunk * 16 + b) * 65536;
  #pragma unroll
  for (int mt = 0; mt < 2; ++mt)
    #pragma unroll
    for (int nt = 0; nt < 2; ++nt)
      #pragma unroll
      for (int r = 0; r < 16; ++r) {
        int row = j0 + mt * 32 + (r & 3) + 8 * (r >> 2) + 4 * (lane >> 5);
        int col = i0 + nt * 32 + (lane & 31);
        op[(size_t)row * 256 + col] = acc[mt][nt][r];
      }
}

// ---------------------------------------------------------------------------
// Reduce Gram partials (8 chunks) -> G2 bf16 [b][j][i]
// ---------------------------------------------------------------------------
__global__ __launch_bounds__(256) void greduce_kernel(
    const float* __restrict__ part, bf16* __restrict__ G2) {
  size_t e = ((size_t)blockIdx.x * 256 + threadIdx.x) * 8;  // grid 512
  float a[8];
  #pragma unroll
  for (int i = 0; i < 8; ++i) a[i] = 0.f;
  #pragma unroll
  for (int ch = 0; ch < 8; ++ch) {
    f32x4 p0 = *(const f32x4*)&part[ch * 1048576ull + e];
    f32x4 p1 = *(const f32x4*)&part[ch * 1048576ull + e + 4];
    #pragma unroll
    for (int i = 0; i < 4; ++i) { a[i] += p0[i]; a[4 + i] += p1[i]; }
  }
  bf16x8 o;
  #pragma unroll
  for (int i = 0; i < 8; ++i) o[i] = (bf16)a[i];
  *(bf16x8*)&G2[e] = o;
}

// ---------------------------------------------------------------------------
// Fold: per (b,h): M1 = Wq_h@G2^T; S = M1@Wk_h^T; softmax -> P;
// UT[b][cin][h*32+c] = sum_d WvT[cin][h*32+d]*P[c][d].
// ---------------------------------------------------------------------------
__global__ __launch_bounds__(256) void fold2_kernel(
    const bf16* __restrict__ G2, const bf16* __restrict__ Wq,
    const bf16* __restrict__ Wk, const bf16* __restrict__ WvT,
    bf16* __restrict__ UT) {
  const int bh = blockIdx.x;
  const int b = bh >> 3, h = bh & 7;
  const int tid = threadIdx.x, lane = tid & 63, w = tid >> 6;
  __shared__ bf16 M1[32 * 256];
  __shared__ float Sp[4][1024];
  __shared__ float S[1024];
  __shared__ bf16 P[1024];

  const bf16* gq = Wq + (size_t)(h * 32) * 256;
  const bf16* g2b = G2 + (size_t)b * 65536;
  #pragma unroll
  for (int mt = 0; mt < 2; ++mt)
    #pragma unroll
    for (int nt = 0; nt < 4; ++nt) {
      f32x4 acc = {0.f, 0.f, 0.f, 0.f};
      #pragma unroll
      for (int ks = 0; ks < 8; ++ks) {
        bf16x8 a = *(const bf16x8*)&gq[(size_t)(mt * 16 + (lane & 15)) * 256 +
                                       ks * 32 + (lane >> 4) * 8];
        bf16x8 bb = *(const bf16x8*)&g2b[
            (size_t)(w * 64 + nt * 16 + (lane & 15)) * 256 + ks * 32 +
            (lane >> 4) * 8];
        acc = mfma16(a, bb, acc);
      }
      #pragma unroll
      for (int r = 0; r < 4; ++r)
        M1[(mt * 16 + (lane >> 4) * 4 + r) * 256 + w * 64 + nt * 16 +
           (lane & 15)] = (bf16)acc[r];
    }
  __syncthreads();

  const bf16* gk = Wk + (size_t)(h * 32) * 256;
  #pragma unroll
  for (int mt = 0; mt < 2; ++mt)
    #pragma unroll
    for (int dt = 0; dt < 2; ++dt) {
      f32x4 acc = {0.f, 0.f, 0.f, 0.f};
      #pragma unroll
      for (int kk = 0; kk < 2; ++kk) {
        bf16x8 a = *(const bf16x8*)&M1[(mt * 16 + (lane & 15)) * 256 + w * 64 +
                                       kk * 32 + (lane >> 4) * 8];
        bf16x8 bb = *(const bf16x8*)&gk[(size_t)(dt * 16 + (lane & 15)) * 256 +
                                        w * 64 + kk * 32 + (lane >> 4) * 8];
        acc = mfma16(a, bb, acc);
      }
      #pragma unroll
      for (int r = 0; r < 4; ++r)
        Sp[w][(mt * 16 + (lane >> 4) * 4 + r) * 32 + dt * 16 + (lane & 15)] =
            acc[r];
    }
  __syncthreads();
  #pragma unroll
  for (int i = 0; i < 4; ++i) {
    int e = tid + 256 * i;
    S[e] = (Sp[0][e] + Sp[1][e] + Sp[2][e] + Sp[3][e]) * 0.17677669529663687f;
  }
  __syncthreads();
  if (tid < 32) {
    float m = -1e30f;
    #pragma unroll
    for (int d = 0; d < 32; ++d) m = fmaxf(m, S[tid * 32 + d]);
    float sum = 0.f;
    float ex[32];
    #pragma unroll
    for (int d = 0; d < 32; ++d) {
      ex[d] = __expf(S[tid * 32 + d] - m);
      sum += ex[d];
    }
    float inv = 1.f / sum;
    #pragma unroll
    for (int d = 0; d < 32; ++d) P[tid * 32 + d] = (bf16)(ex[d] * inv);
  }
  __syncthreads();

  bf16x8 bfrag[2];
  #pragma unroll
  for (int ct = 0; ct < 2; ++ct)
    bfrag[ct] =
        *(const bf16x8*)&P[(ct * 16 + (lane & 15)) * 32 + (lane >> 4) * 8];
  bf16* outb = UT + (size_t)b * 65536 + h * 32;
  #pragma unroll
  for (int t = 0; t < 4; ++t) {
    int cin16 = w * 64 + t * 16;
    bf16x8 afrag = *(const bf16x8*)&WvT[(size_t)(cin16 + (lane & 15)) * 256 +
                                        h * 32 + (lane >> 4) * 8];
    #pragma unroll
    for (int ct = 0; ct < 2; ++ct) {
      f32x4 acc = {0.f, 0.f, 0.f, 0.f};
      acc = mfma16(afrag, bfrag[ct], acc);
      int c = ct * 16 + (lane & 15);
      int cinr = cin16 + (lane >> 4) * 4;
      #pragma unroll
      for (int r = 0; r < 4; ++r)
        outb[(size_t)(cinr + r) * 256 + c] = (bf16)acc[r];
    }
  }
}

// ---------------------------------------------------------------------------
// Small GEMM for Wfold: out bf16 [b][256][256] = Wo @ UT   (128x128 tiles)
// ---------------------------------------------------------------------------
__global__ __launch_bounds__(256) void wfold_kernel(
    const bf16* __restrict__ Aw, const bf16* __restrict__ Bx,
    bf16* __restrict__ outp) {
  const int tid = threadIdx.x;
  const int lane = tid & 63;
  const int wave = tid >> 6;
  const int wr = wave >> 1, wc = wave & 1;
  const int l0 = blockIdx.x * 128;
  const int m0 = blockIdx.y * 128;
  const int b  = blockIdx.z;
  constexpr int NB = 4096;
  __shared__ bf16 smem[4 * NB];
  bf16* As = smem;
  bf16* Bs = smem + 2 * NB;
  const bf16* Ag = Aw + (size_t)m0 * 256;
  const bf16* Bg = Bx + ((size_t)b * 256 + l0) * 256;
  auto stage = [&](int buf, int k0) {
    #pragma unroll
    for (int i = 0; i < 2; ++i) {
      int ch = i * 256 + tid;
      int r  = ch >> 2;
      int c8 = (ch & 3) * 8;
      gl2lds16(Ag + (size_t)r * 256 + k0 + c8, As + buf * NB + ch * 8);
      gl2lds16(Bg + (size_t)r * 256 + k0 + c8, Bs + buf * NB + ch * 8);
    }
  };
  f32x4 acc[4][4];
  #pragma unroll
  for (int mi = 0; mi < 4; ++mi)
    #pragma unroll
    for (int ni = 0; ni < 4; ++ni)
      #pragma unroll
      for (int r = 0; r < 4; ++r) acc[mi][ni][r] = 0.f;
  stage(0, 0);
  for (int kt = 0; kt < 8; ++kt) {
    __syncthreads();
    if (kt + 1 < 8) stage((kt + 1) & 1, (kt + 1) * 32);
    const bf16* Ab = As + (kt & 1) * NB;
    const bf16* Bb = Bs + (kt & 1) * NB;
    bf16x8 af[4], bfr[4];
    #pragma unroll
    for (int mi = 0; mi < 4; ++mi)
      af[mi] = *(const bf16x8*)&Ab[(wr * 64 + mi * 16 + (lane & 15)) * 32 +
                                   (lane >> 4) * 8];
    #pragma unroll
    for (int ni = 0; ni < 4; ++ni)
      bfr[ni] = *(const bf16x8*)&Bb[(wc * 64 + ni * 16 + (lane & 15)) * 32 +
                                    (lane >> 4) * 8];
    #pragma unroll
    for (int mi = 0; mi < 4; ++mi)
      #pragma unroll
      for (int ni = 0; ni < 4; ++ni)
        acc[mi][ni] = mfma16(af[mi], bfr[ni], acc[mi][ni]);
  }
  const int mq = m0 + wr * 64 + (lane >> 4) * 4;
  const int lq = l0 + wc * 64 + (lane & 15);
  #pragma unroll
  for (int mi = 0; mi < 4; ++mi)
    #pragma unroll
    for (int ni = 0; ni < 4; ++ni) {
      int l = lq + ni * 16, mb = mq + mi * 16;
      #pragma unroll
      for (int r = 0; r < 4; ++r)
        outp[((size_t)b * 256 + mb + r) * 256 + l] = (bf16)acc[mi][ni][r];
    }
}

// ---------------------------------------------------------------------------
// Fused x-GEMM + residual + LN-stats, R9 geometry: 256x128 tile, 8 waves,
// BK=32 dbuf (48 KB + 2 KB red), grid (32 l-tiles, 16 b). A = Wfold[b]
// (256x256), B = sar_lc rows. Epilogue: bf16 opt_raw residual + X write
// DIRECT from acc (no LDS transpose) + per-l stats via shfl+LDS reduce.
// ---------------------------------------------------------------------------
__global__ __launch_bounds__(512, 4) void xgemm_stats_kernel(
    const bf16* __restrict__ Wfold, const bf16* __restrict__ sar_lc,
    const bf16* __restrict__ opt_raw, bf16* __restrict__ xout,
    float* __restrict__ stats) {
  __shared__ __align__(16) char smem[51200];
  float* red = (float*)(smem + 49152);       // [2][2][128] f32 = 2 KB
  const int tid = threadIdx.x;
  const int lane = tid & 63;
  const int wave = tid >> 6;
  const int wr = wave >> 2;        // 0..1 (c half: 128 rows of Wfold)
  const int wc = wave & 3;         // 0..3 (l quarter: 32 l)
  const int l0 = blockIdx.x * 128;
  const int b  = blockIdx.y;
  const int qq = lane >> 4;
  const int lr = lane & 15;

  const bf16* Ag = Wfold + (size_t)b * 65536;
  const bf16* Bg = sar_lc + ((size_t)b * LSP + l0) * CCH;

  auto stage = [&](int buf, int kt) {
    char* la = smem + (buf << 14);
    char* lb2 = smem + 32768 + (buf << 13);
    #pragma unroll
    for (int i = 0; i < 2; ++i) {
      int qi = i * 512 + tid;                 // 0..1023 A-chunks
      int r = qi >> 2, c = qi & 3;
      int gc = c ^ ((r >> 1) & 3);
      gl2lds16(Ag + (size_t)r * 256 + kt * 32 + gc * 8,
               (bf16*)(la + qi * 16));
    }
    {
      int r = tid >> 2, c = tid & 3;          // 512 B-chunks (128 rows)
      int gc = c ^ ((r >> 1) & 3);
      gl2lds16(Bg + (size_t)r * 256 + kt * 32 + gc * 8,
               (bf16*)(lb2 + tid * 16));
    }
  };

  f32x4 acc[8][2];
  #pragma unroll
  for (int mi = 0; mi < 8; ++mi)
    #pragma unroll
    for (int ni = 0; ni < 2; ++ni)
      #pragma unroll
      for (int r = 0; r < 4; ++r) acc[mi][ni][r] = 0.f;

  stage(0, 0);
  for (int kt = 0; kt < 8; ++kt) {
    __syncthreads();
    if (kt + 1 < 8) stage((kt + 1) & 1, kt + 1);
    const char* Ab = smem + ((kt & 1) << 14);
    const char* Bb = smem + 32768 + ((kt & 1) << 13);
    bf16x8 af[8], bf2[2];
    #pragma unroll
    for (int mi = 0; mi < 8; ++mi) {
      int row = wr * 128 + mi * 16 + lr;
      int c = qq ^ ((row >> 1) & 3);
      af[mi] = *(const bf16x8*)(Ab + row * 64 + c * 16);
    }
    #pragma unroll
    for (int ni = 0; ni < 2; ++ni) {
      int row = wc * 32 + ni * 16 + lr;
      int c = qq ^ ((row >> 1) & 3);
      bf2[ni] = *(const bf16x8*)(Bb + row * 64 + c * 16);
    }
    #pragma unroll
    for (int mi = 0; mi < 8; ++mi)
      #pragma unroll
      for (int ni = 0; ni < 2; ++ni)
        acc[mi][ni] = mfma16(af[mi], bf2[ni], acc[mi][ni]);
  }

  // epilogue: c = wr*128 + mi*16 + qq*4 + r; l = wc*32 + ni*16 + lr
  float s[2] = {0.f, 0.f}, q[2] = {0.f, 0.f};
  #pragma unroll
  for (int mi = 0; mi < 8; ++mi) {
    int c = wr * 128 + mi * 16 + qq * 4;
    #pragma unroll
    for (int ni = 0; ni < 2; ++ni) {
      int l = wc * 32 + ni * 16 + lr;
      const size_t base = ((size_t)b * LSP + l0 + l) * CCH + c;
      bf16x4 o4 = *(const bf16x4*)&opt_raw[base];
      bf16x4 hx;
      #pragma unroll
      for (int r = 0; r < 4; ++r) {
        float v = acc[mi][ni][r] + (float)o4[r];
        s[ni] += v; q[ni] += v * v;
        hx[r] = (bf16)v;
      }
      *(bf16x4*)&xout[base] = hx;
    }
  }
  // reduce over qq (4 c-quads x 8 mi = full 128 c of this wr-half)
  #pragma unroll
  for (int ni = 0; ni < 2; ++ni) {
    s[ni] += __shfl_xor(s[ni], 16);
    s[ni] += __shfl_xor(s[ni], 32);
    q[ni] += __shfl_xor(q[ni], 16);
    q[ni] += __shfl_xor(q[ni], 32);
  }
  __syncthreads();   // stage region fully read (loop done); red is separate
  if (qq == 0) {
    #pragma unroll
    for (int ni = 0; ni < 2; ++ni) {
      int ll = wc * 32 + ni * 16 + lr;
      red[(wr * 2 + 0) * 128 + ll] = s[ni];
      red[(wr * 2 + 1) * 128 + ll] = q[ni];
    }
  }
  __syncthreads();
  if (tid < 128) {
    float S = red[0 * 128 + tid] + red[2 * 128 + tid];
    float Q = red[1 * 128 + tid] + red[3 * 128 + tid];
    float m = S * (1.f / 256.f);
    float rs = rsqrtf(Q * (1.f / 256.f) - m * m + 1e-5f);
    float* st = stats + ((size_t)b * LSP + l0 + tid) * 2;
    st[0] = m;
    st[1] = rs;
  }
}

// ---------------------------------------------------------------------------
// 256x256-tile 8-phase GEMM, gray-code quadrant order with B register-cached
// (R8 proven). MODE 0 (KEL=256): W1g -> folded-LN + SimpleGate, bf16
// [b][l][512]. MODE 1 (KEL=512): W2 -> + b2 + res(bf16 x), f32 d_out.
// ---------------------------------------------------------------------------
template <int KEL, int MODE>
__global__ __launch_bounds__(512, 2) void ffn_gemm_kernel(
    const bf16* __restrict__ Aw, const bf16* __restrict__ Bx,
    void* __restrict__ outp, const bf16* __restrict__ resb,
    const float* __restrict__ bias, const float* __restrict__ stats) {
  constexpr int LDSB = (MODE == 1) ? 135168 : 131072;
  __shared__ __align__(16) char smem_raw[LDSB];
  const int tid = threadIdx.x;
  const int lane = tid & 63;
  const int wave = tid >> 6;
  const int wr = wave >> 2;
  const int wc = wave & 3;
  const int l0 = blockIdx.x * 256;
  const int m0 = blockIdx.y * 256;
  const int b  = blockIdx.z;

  char* ldsA0 = smem_raw;
  char* ldsB0 = smem_raw + 32768;
  char* ldsA1 = smem_raw + 65536;
  char* ldsB1 = smem_raw + 98304;

  const bf16* Ag = Aw + (size_t)m0 * KEL;
  const bf16* Bg = Bx + ((size_t)b * LSP + l0) * KEL;

  auto STAGE = [&](const bf16* gsrc, char* ldst, int par, int kt) {
    #pragma unroll
    for (int i = 0; i < 2; ++i) {
      int qi = i * 512 + tid;
      int r  = ((qi >> 7) << 5) + (par << 4) + ((qi >> 3) & 15);
      int cl = (qi & 7) ^ ((qi >> 3) & 7);
      int p  = ((qi >> 7) << 8) + (par << 7) + (qi & 127);
      gl2lds16(gsrc + (size_t)r * KEL + kt * 64 + cl * 8,
               (bf16*)(ldst + p * 16));
    }
  };

  f32x4 acc[8][4];
  #pragma unroll
  for (int mi = 0; mi < 8; ++mi)
    #pragma unroll
    for (int ni = 0; ni < 4; ++ni)
      #pragma unroll
      for (int r = 0; r < 4; ++r) acc[mi][ni][r] = 0.f;

  bf16x8 af[4][2], bn0[2][2], bn1[2][2];
  const int col0 = (((lane >> 4) << 4)) ^ ((lane & 7) << 4);
  const int col1 = col0 ^ 64;
  const int arow_off = (lane & 15) * 128;

#define LOAD_A(BUFA, MP)                                                      \
  {                                                                           \
    const char* Ab_ = (BUFA);                                                 \
    _Pragma("unroll") for (int j = 0; j < 4; ++j) {                           \
      int rb = (wr * 128 + ((MP) + 2 * j) * 16) * 128 + arow_off;             \
      af[j][0] = *(const bf16x8*)(Ab_ + rb + col0);                           \
      af[j][1] = *(const bf16x8*)(Ab_ + rb + col1);                           \
    }                                                                         \
  }

#define LOAD_B(BUFB, NP, DST)                                                 \
  {                                                                           \
    const char* Bb_ = (BUFB);                                                 \
    _Pragma("unroll") for (int i = 0; i < 2; ++i) {                           \
      int rb = (wc * 64 + ((NP) + 2 * i) * 16) * 128 + arow_off;              \
      DST[i][0] = *(const bf16x8*)(Bb_ + rb + col0);                          \
      DST[i][1] = *(const bf16x8*)(Bb_ + rb + col1);                          \
    }                                                                         \
  }

#define DO_MFMA(MP, NP, BS)                                                   \
  _Pragma("unroll") for (int j = 0; j < 4; ++j)                               \
  _Pragma("unroll") for (int i = 0; i < 2; ++i) {                             \
    acc[(MP) + 2 * j][(NP) + 2 * i] =                                         \
        mfma16(af[j][0], BS[i][0], acc[(MP) + 2 * j][(NP) + 2 * i]);          \
    acc[(MP) + 2 * j][(NP) + 2 * i] =                                         \
        mfma16(af[j][1], BS[i][1], acc[(MP) + 2 * j][(NP) + 2 * i]);          \
  }

#define PH_HEAD                                                               \
  asm volatile("s_waitcnt vmcnt(6)" ::: "memory");                            \
  __builtin_amdgcn_s_barrier();                                               \
  __builtin_amdgcn_sched_barrier(0);

#define PH_TAIL(MP, NP, BS)                                                   \
  asm volatile("s_waitcnt lgkmcnt(0)" ::: "memory");                          \
  __builtin_amdgcn_sched_barrier(0);                                         \
  __builtin_amdgcn_s_setprio(1);                                              \
  DO_MFMA(MP, NP, BS);                                                        \
  __builtin_amdgcn_s_setprio(0);

  STAGE(Ag, ldsA0, 0, 0);
  STAGE(Bg, ldsB0, 0, 0);
  STAGE(Bg, ldsB0, 1, 0);
  STAGE(Ag, ldsA0, 1, 0);
  STAGE(Ag, ldsA1, 0, 1);
  STAGE(Bg, ldsB1, 1, 1);

  constexpr int NITER = KEL / 128;
  constexpr int KMAX = KEL / 64 - 1;
  for (int t = 0; t < NITER; ++t) {
    const int k1 = 2 * t + 1;
    const int k2 = (2 * t + 2 > KMAX) ? KMAX : 2 * t + 2;
    const int k3 = (2 * t + 3 > KMAX) ? KMAX : 2 * t + 3;
    PH_HEAD; LOAD_A(ldsA0, 0); LOAD_B(ldsB0, 0, bn0);
    STAGE(Bg, ldsB1, 0, k1); STAGE(Ag, ldsA1, 1, k1);
    PH_TAIL(0, 0, bn0);
    PH_HEAD; LOAD_B(ldsB0, 1, bn1);
    PH_TAIL(0, 1, bn1);
    PH_HEAD; LOAD_A(ldsA0, 1); STAGE(Ag, ldsA0, 0, k2);
    PH_TAIL(1, 1, bn1);
    PH_HEAD; STAGE(Bg, ldsB0, 1, k2);
    PH_TAIL(1, 0, bn0);
    PH_HEAD; LOAD_A(ldsA1, 0); LOAD_B(ldsB1, 0, bn0);
    STAGE(Bg, ldsB0, 0, k2);
    PH_TAIL(0, 0, bn0);
    PH_HEAD; LOAD_B(ldsB1, 1, bn1); STAGE(Ag, ldsA0, 1, k2);
    PH_TAIL(0, 1, bn1);
    PH_HEAD; LOAD_A(ldsA1, 1); STAGE(Ag, ldsA1, 0, k3);
    PH_TAIL(1, 1, bn1);
    PH_HEAD; STAGE(Bg, ldsB1, 1, k3);
    PH_TAIL(1, 0, bn0);
  }
#undef PH_HEAD
#undef PH_TAIL
#undef DO_MFMA
#undef LOAD_A
#undef LOAD_B

  asm volatile("s_waitcnt vmcnt(0)" ::: "memory");
  __syncthreads();

  if constexpr (MODE == 0) {
    bf16* g_lds = (bf16*)smem_raw;           // [256 l][136 pad]
    const int lq = wc * 64 + (lane & 15);
    const int qq = (lane >> 4);
    const float* stb = stats + ((size_t)b * LSP + l0) * 2;
    float muv[4], rsv[4];
    #pragma unroll
    for (int ni = 0; ni < 4; ++ni) {
      int l = lq + ni * 16;
      muv[ni] = stb[l * 2];
      rsv[ni] = stb[l * 2 + 1];
    }
    #pragma unroll
    for (int mi = 0; mi < 8; ++mi) {
      int a0 = wr * 64 + mi * 8 + qq * 2;
      int ag = (m0 >> 1) + a0;
      float be1a = bias[ag],        ga1a = bias[512 + ag];
      float be2a = bias[1024 + ag], ga2a = bias[1536 + ag];
      float be1b = bias[ag + 1],        ga1b = bias[512 + ag + 1];
      float be2b = bias[1024 + ag + 1], ga2b = bias[1536 + ag + 1];
      #pragma unroll
      for (int ni = 0; ni < 4; ++ni) {
        int l = lq + ni * 16;
        float mrs = muv[ni] * rsv[ni];
        float h1a = rsv[ni] * acc[mi][ni][0] + be1a - mrs * ga1a;
        float h2a = rsv[ni] * acc[mi][ni][1] + be2a - mrs * ga2a;
        float h1b = rsv[ni] * acc[mi][ni][2] + be1b - mrs * ga1b;
        float h2b = rsv[ni] * acc[mi][ni][3] + be2b - mrs * ga2b;
        bf16 gv0 = (bf16)(h1a * h2a), gv1 = (bf16)(h1b * h2b);
        unsigned u = ((unsigned)*(unsigned short*)&gv1 << 16) |
                     (unsigned)*(unsigned short*)&gv0;
        *(unsigned*)&g_lds[l * 136 + a0] = u;
      }
    }
    __syncthreads();
    bf16* out = (bf16*)outp;
    const int gy = blockIdx.y * 128;
    #pragma unroll
    for (int it = 0; it < 8; ++it) {
      int cid = it * 512 + tid;
      int l = cid >> 4, ch = cid & 15;
      bf16x8 v = *(const bf16x8*)&g_lds[l * 136 + ch * 8];
      *(bf16x8*)&out[((size_t)b * LSP + l0 + l) * 512 + gy + ch * 8] = v;
    }
  } else {
    float* lds_f = (float*)smem_raw;         // [128 c][260 pad]
    float* out = (float*)outp;
    const int lq = wc * 64 + (lane & 15);
    const int qq = (lane >> 4);
    #pragma unroll
    for (int round = 0; round < 2; ++round) {
      if (wr == round) {
        #pragma unroll
        for (int mi = 0; mi < 8; ++mi) {
          int c0 = mi * 16 + qq * 4;
          f32x4 b4 = *(const f32x4*)&bias[round * 128 + c0];
          #pragma unroll
          for (int ni = 0; ni < 4; ++ni) {
            int l = lq + ni * 16;
            bf16x4 xr4 = *(const bf16x4*)&resb[((size_t)b * LSP + l0 + l) *
                                                   CCH + round * 128 + c0];
            #pragma unroll
            for (int r = 0; r < 4; ++r)
              lds_f[(c0 + r) * 260 + l] =
                  acc[mi][ni][r] + b4[r] + (float)xr4[r];
          }
        }
      }
      __syncthreads();
      #pragma unroll
      for (int it = 0; it < 16; ++it) {
        int cid = it * 512 + tid;
        int c = cid >> 6, lch = cid & 63;
        f32x4 v = *(const f32x4*)&lds_f[c * 260 + lch * 4];
        *(f32x4*)&out[((size_t)b * CCH + round * 128 + c) * LSP + l0 +
                      lch * 4] = v;
      }
      __syncthreads();
    }
  }
}

// ---------------------------------------------------------------------------
extern "C" void kernel_launch(void* const* d_in, const int* in_sizes, int n_in,
                              void* d_out, int out_size, void* d_ws,
                              size_t ws_size, hipStream_t stream) {
  const float* optical = (const float*)d_in[0];
  const float* sar     = (const float*)d_in[1];
  const float* g_opt   = (const float*)d_in[2];
  const float* b_opt   = (const float*)d_in[3];
  const float* g_sar   = (const float*)d_in[4];
  const float* b_sar   = (const float*)d_in[5];
  const float* Wq      = (const float*)d_in[6];
  const float* Wk      = (const float*)d_in[7];
  const float* Wv      = (const float*)d_in[8];
  const float* Wo      = (const float*)d_in[9];
  const float* g_ffn   = (const float*)d_in[10];
  const float* b_ffn   = (const float*)d_in[11];
  const float* W1      = (const float*)d_in[12];
  const float* b1      = (const float*)d_in[13];
  const float* W2      = (const float*)d_in[14];
  const float* b2      = (const float*)d_in[15];

  char* ws = (char*)d_ws;
  bf16* wbf  = (bf16*)ws;
  bf16* Wqb  = wbf;
  bf16* Wkb  = wbf + 65536;
  bf16* WvTb = wbf + 131072;
  bf16* Wob  = wbf + 196608;
  bf16* W1b  = wbf + 262144;   // interleaved, pre-scaled by g_ffn
  bf16* W2b  = wbf + 524288;

  size_t off = 2ull * 1024 * 1024;
  const size_t T16 = 16ull * LSP * CCH * 2;  // 33.5 MB bf16 tensor
  bf16* opt_ncl = (bf16*)(ws + off); off += T16;
  bf16* sar_ncl = (bf16*)(ws + off); off += T16;
  bf16* sar_nlc = (bf16*)(ws + off); off += T16;
  bf16* opt_raw = (bf16*)(ws + off); off += T16;                   // raw bf16
  bf16* xb      = (bf16*)(ws + off); off += T16;                   // x bf16
  float* stats  = (float*)(ws + off); off += 1ull * 1024 * 1024;   // 512KB+
  float* cvec   = (float*)(ws + off); off += 64 * 1024;            // 8KB
  float* Gpart  = (float*)(ws + off); off += 34ull * 1024 * 1024;  // 33.5 MB
  bf16* G2b     = (bf16*)(ws + off); off += 4ull * 1024 * 1024;
  bf16* UTb     = (bf16*)(ws + off); off += 2ull * 1024 * 1024;
  bf16* Wfoldb  = (bf16*)(ws + off); off += 2ull * 1024 * 1024;
  bf16* gbuf = opt_ncl;  // 67 MB overlay (opt_ncl+sar_ncl dead after gram)

  dim3 blk(256);
  cvt_w_kernel<<<2564, blk, 0, stream>>>(Wq, Wk, Wv, Wo, W1, W2, g_ffn, b_ffn,
                                         b1, wbf, cvec);
  ln_both_kernel<<<dim3(64, 16, 2), blk, 0, stream>>>(
      optical, sar, g_opt, b_opt, g_sar, b_sar, opt_ncl, opt_raw, sar_ncl,
      sar_nlc);
  gram_kernel<<<dim3(4, 8, 16), blk, 0, stream>>>(sar_ncl, opt_ncl, Gpart);
  greduce_kernel<<<512, blk, 0, stream>>>(Gpart, G2b);
  fold2_kernel<<<128, blk, 0, stream>>>(G2b, Wqb, Wkb, WvTb, UTb);
  wfold_kernel<<<dim3(2, 2, 16), blk, 0, stream>>>(Wob, UTb, Wfoldb);
  xgemm_stats_kernel<<<dim3(32, 16), dim3(512), 0, stream>>>(
      Wfoldb, sar_nlc, opt_raw, xb, stats);
  ffn_gemm_kernel<256, 0><<<dim3(16, 4, 16), dim3(512), 0, stream>>>(
      W1b, xb, gbuf, nullptr, cvec, stats);
  ffn_gemm_kernel<512, 1><<<dim3(16, 1, 16), dim3(512), 0, stream>>>(
      W2b, gbuf, (float*)d_out, xb, b2, nullptr);
}